// Round 5
// baseline (572.733 us; speedup 1.0000x reference)
//
#include <hip/hip_runtime.h>
#include <stdint.h>

typedef unsigned short u16;
typedef unsigned int u32;
typedef __attribute__((ext_vector_type(8))) __bf16 bf16x8;
typedef __attribute__((ext_vector_type(8))) u16 u16x8;
typedef __attribute__((ext_vector_type(4))) float f32x4;
typedef __attribute__((ext_vector_type(4))) u32 u32x4;

#define DEV static __device__ __forceinline__

namespace {

constexpr int NB2  = 2;
constexpr int SEQL = 8192;
constexpr int EMB  = 1024;
constexpr int HD   = 64;
constexpr int NLM  = 64;
constexpr int NTOK = NB2 * SEQL;   // 16384

// workspace layout (bytes)
constexpr size_t OFF_QBF  = 0;                          // query bf16   33554432
constexpr size_t OFF_WBF  = OFF_QBF  + 33554432;        // 4 weights    8388608
constexpr size_t OFF_QKV  = OFF_WBF  + 8388608;         // Q,K,V bf16   100663296
constexpr size_t OFF_ATT  = OFF_QKV  + 100663296;       // attn bf16    33554432
constexpr size_t OFF_LAND = OFF_ATT  + 33554432;        // landmarks    262144
constexpr size_t OFF_LN   = OFF_LAND + 262144;          // |l|^2 f32    8192
constexpr size_t OFF_WK   = OFF_LN   + 8192;            // W kernel f32 -> Winv (in-place) 524288
constexpr size_t OFF_ZP   = OFF_WK   + 524288;          // Z partials   4194304
constexpr size_t OFF_SP   = OFF_ZP   + 4194304;         // sum partials 65536
constexpr size_t OFF_YT   = OFF_SP   + 65536;           // Y^T bf16     327680

DEV u16 f2bf(float f){
  u32 u = __builtin_bit_cast(u32, f);
  u32 r = (u + 0x7FFFu + ((u >> 16) & 1u)) >> 16;
  return (u16)r;
}
DEV float bf2f(u16 h){ u32 u = ((u32)h) << 16; return __builtin_bit_cast(float, u); }
DEV u16x8 ld8(const u16* p){ return *(const u16x8*)p; }
DEV f32x4 mfma16(u16x8 a, u16x8 b, f32x4 c){
  return __builtin_amdgcn_mfma_f32_16x16x32_bf16(
      __builtin_bit_cast(bf16x8, a), __builtin_bit_cast(bf16x8, b), c, 0, 0, 0);
}
// async global->LDS, 16B per lane; LDS dest is wave-uniform base + lane*16.
DEV void gld_lds16(void* lds, const void* g){
  __builtin_amdgcn_global_load_lds(
      (__attribute__((address_space(1))) void*)(uintptr_t)g,
      (__attribute__((address_space(3))) void*)(u32)(uintptr_t)lds,
      16, 0, 0);
}
DEV void vmwait4(){ asm volatile("s_waitcnt vmcnt(4)" ::: "memory"); }
DEV void vmwait0(){ asm volatile("s_waitcnt vmcnt(0)" ::: "memory"); }
DEV void barrier_pin(){
  __builtin_amdgcn_s_barrier();
  __builtin_amdgcn_sched_barrier(0);
}
// LDS physical<->logical byte permutation within a 16KB half-tile:
// rows are 128B (=32 banks), so fr contributes 0 bank spread; XOR the
// 16B-slot index (bits 4-6) with row bits 0-2 (bits 7-9). Involution.
DEV u32 swz(u32 a){ return a ^ (((a >> 7) & 7u) << 4); }
DEV float rdlane(float v, int l){
  return __builtin_bit_cast(float, __builtin_amdgcn_readlane(__builtin_bit_cast(int, v), l));
}

// ---------------- fp32 -> bf16 pack ----------------
__global__ __launch_bounds__(256) void k_cvt(const float* __restrict__ src,
                                             u16* __restrict__ dst, int n8){
  int i = blockIdx.x * blockDim.x + threadIdx.x;
  if (i >= n8) return;
  float t[8];
  *(float4*)&t[0] = ((const float4*)src)[2*i];
  *(float4*)&t[4] = ((const float4*)src)[2*i + 1];
  u16x8 o;
  #pragma unroll
  for (int j = 0; j < 8; ++j) o[j] = f2bf(t[j]);
  *(u16x8*)&dst[(size_t)i * 8] = o;
}

// ---------------- 256x256 8-phase GEMM (m201-style template) ----------------
// C[m][n] = sum_k A[m][k] * W[n][k] (+bias). BK=64, 2 K-tiles/iter, 8 waves.
// MODE 0: fused QKV (3 weight mats, bf16 out). MODE 1: out-proj (f32 out).
template <int MODE>
__global__ __launch_bounds__(512, 2) void k_gemm256(
    const u16* __restrict__ A, const u16* __restrict__ Wb,
    const float* __restrict__ b0, const float* __restrict__ b1,
    const float* __restrict__ b2, u16* __restrict__ OutB, float* __restrict__ OutF)
{
  constexpr int NI = 8;                       // iterations (2 K-tiles each), K=1024
  __shared__ __align__(16) u16 lds[2][2][2][128*64];   // [buf][mat][half][row*64+k]
  const int tid = threadIdx.x, lane = tid & 63, wv = tid >> 6;
  const int wr = wv >> 2, wc = wv & 3;        // 2 x 4 wave grid
  const int fr = lane & 15, fk = (lane >> 4) * 8;

  constexpr int NBX = (MODE == 0) ? 12 : 4;
  constexpr int CPX = NBX * 64 / 8;           // blocks per XCD chunk
  const int lin = blockIdx.x + NBX * blockIdx.y;
  const int w = (lin & 7) * CPX + (lin >> 3); // bijective XCD chunk swizzle
  const int bxw = w % NBX, byw = w / NBX;
  const int wsel = (MODE == 0) ? (bxw >> 2) : 0;
  const int col0 = (MODE == 0) ? ((bxw & 3) * 256) : (bxw * 256);
  const int row0 = byw * 256;
  const u16* Bm = Wb + (size_t)wsel * EMB * EMB;

  // staging: linear LDS dest byte P holds logical byte swz(P)
  int voff[2]; u32 lo_[2];
  #pragma unroll
  for (int j = 0; j < 2; ++j) {
    u32 P  = (u32)((j*8 + wv) * 1024);
    u32 Pl = P + (u32)lane * 16;
    u32 L  = swz(Pl);
    voff[j] = (int)((L >> 7) * EMB + ((L >> 1) & 63));
    lo_[j]  = P;
  }
  // swizzled per-lane ds_read byte offsets (row = fr within each 16-row stripe)
  u32 qsw[2];
  #pragma unroll
  for (int ks = 0; ks < 2; ++ks)
    qsw[ks] = swz((u32)(fr*128 + ks*64 + fk*2));

  f32x4 acc[8][4] = {};
  u16x8 af[2][8], bfr[2][4];

  auto STAGE = [&](int buf, int mat, int half, int kt) {
    const u16* gb = (mat == 0)
      ? (A  + (size_t)(row0 + half*128) * EMB + kt*64)
      : (Bm + (size_t)(col0 + half*128) * EMB + kt*64);
    char* lb = (char*)&lds[buf][mat][half][0];
    #pragma unroll
    for (int j = 0; j < 2; ++j)
      gld_lds16(lb + lo_[j], gb + voff[j]);
  };
  auto LDA = [&](int buf, int m, int ks) -> u16x8 {
    return ld8((const u16*)((const char*)&lds[buf][0][wr][0] + m*2048 + qsw[ks]));
  };
  auto LDB = [&](int buf, int n, int ks) -> u16x8 {
    return ld8((const u16*)((const char*)&lds[buf][1][wc>>1][0]
                            + (wc&1)*8192 + n*2048 + qsw[ks]));
  };
  auto READ_LO = [&](int buf) {       // A m0-3 + B n0-1 (both ks): 12 ds_read_b128
    #pragma unroll
    for (int ks = 0; ks < 2; ++ks) {
      #pragma unroll
      for (int m = 0; m < 4; ++m) af[ks][m] = LDA(buf, m, ks);
      #pragma unroll
      for (int n = 0; n < 2; ++n) bfr[ks][n] = LDB(buf, n, ks);
    }
  };
  auto READ_HI = [&](int buf) {       // A m4-7 + B n2-3
    #pragma unroll
    for (int ks = 0; ks < 2; ++ks) {
      #pragma unroll
      for (int m = 0; m < 4; ++m) af[ks][4+m] = LDA(buf, 4+m, ks);
      #pragma unroll
      for (int n = 0; n < 2; ++n) bfr[ks][2+n] = LDB(buf, 2+n, ks);
    }
  };
  auto MFMAQ = [&](int mh, int nh) {  // one C-quadrant x K=64: 16 MFMA
    __builtin_amdgcn_s_setprio(1);
    #pragma unroll
    for (int ks = 0; ks < 2; ++ks)
      #pragma unroll
      for (int m = 0; m < 4; ++m)
        #pragma unroll
        for (int n = 0; n < 2; ++n) {
          const int mi = mh*4 + m, ni = nh*2 + n;
          acc[mi][ni] = mfma16(af[ks][mi], bfr[ks][ni], acc[mi][ni]);
        }
    __builtin_amdgcn_s_setprio(0);
  };

  // prologue: K0 full -> buf0; K1.A0,A1 -> buf1; wait K0 landed
  STAGE(0,0,0,0); STAGE(0,0,1,0); STAGE(0,1,0,0); STAGE(0,1,1,0);
  STAGE(1,0,0,1); STAGE(1,0,1,1);
  vmwait4();
  barrier_pin();

  #pragma unroll 1
  for (int it = 0; it < NI; ++it) {
    const int kt0 = 2*it;
    const bool last = (it == NI-1);
    // ph1: reads buf0 lo; stage (kt0+1).B0 -> buf1
    READ_LO(0); STAGE(1,1,0,kt0+1);
    barrier_pin(); MFMAQ(0,0); barrier_pin();
    // ph2: reads buf0 hi; stage (kt0+1).B1 -> buf1
    READ_HI(0); STAGE(1,1,1,kt0+1);
    barrier_pin(); MFMAQ(0,1); barrier_pin();
    // ph3: stage (kt0+2).A0 -> buf0 (buf0 fully read after ph2)
    if (!last) STAGE(0,0,0,kt0+2);
    barrier_pin(); MFMAQ(1,1); barrier_pin();
    // ph4: stage (kt0+2).A1; counted wait -> buf1 (kt0+1) fully landed
    if (!last) { STAGE(0,0,1,kt0+2); vmwait4(); } else { vmwait0(); }
    barrier_pin(); MFMAQ(1,0); barrier_pin();
    // ph5: reads buf1 lo; stage (kt0+2).B0 -> buf0
    READ_LO(1); if (!last) STAGE(0,1,0,kt0+2);
    barrier_pin(); MFMAQ(0,0); barrier_pin();
    // ph6: reads buf1 hi; stage (kt0+2).B1 -> buf0
    READ_HI(1); if (!last) STAGE(0,1,1,kt0+2);
    barrier_pin(); MFMAQ(0,1); barrier_pin();
    // ph7: stage (kt0+3).A0 -> buf1 (buf1 fully read after ph6)
    if (!last) STAGE(1,0,0,kt0+3);
    barrier_pin(); MFMAQ(1,1); barrier_pin();
    // ph8: stage (kt0+3).A1; counted wait -> buf0 (kt0+2) fully landed
    if (!last) { STAGE(1,0,1,kt0+3); vmwait4(); }
    barrier_pin(); MFMAQ(1,0); barrier_pin();
  }

  // epilogue
  const int rgrp = (lane >> 4) * 4;
  if (MODE == 0) {
    const float* bias = (wsel == 0) ? b0 : ((wsel == 1) ? b1 : b2);
    u16* Out = OutB + (size_t)wsel * NTOK * EMB;
    #pragma unroll
    for (int m = 0; m < 8; ++m) {
      const int r0 = row0 + wr*128 + m*16 + rgrp;
      #pragma unroll
      for (int n = 0; n < 4; ++n) {
        const int c = col0 + wc*64 + n*16 + fr;
        const float bb = bias[c];
        #pragma unroll
        for (int j = 0; j < 4; ++j)
          Out[(size_t)(r0 + j)*EMB + c] = f2bf(acc[m][n][j] + bb);
      }
    }
  } else {
    #pragma unroll
    for (int m = 0; m < 8; ++m) {
      const int r0 = row0 + wr*128 + m*16 + rgrp;
      #pragma unroll
      for (int n = 0; n < 4; ++n) {
        const int c = col0 + wc*64 + n*16 + fr;
        const float bb = b0[c];
        #pragma unroll
        for (int j = 0; j < 4; ++j)
          OutF[(size_t)(r0 + j)*EMB + c] = acc[m][n][j] + bb;
      }
    }
  }
}

// ---------------- landmarks: gather, norms, W kernel ----------------
__global__ __launch_bounds__(256) void k_land(
    const u16* __restrict__ QKV, const int* __restrict__ lidx,
    const float* __restrict__ tempp,
    u16* __restrict__ land, float* __restrict__ lnorm, float* __restrict__ wker)
{
  const int bh = blockIdx.x;            // 0..31
  const int b = bh >> 4, h = bh & 15;
  const int tid = threadIdx.x;
  __shared__ __align__(16) u16 Ls[NLM*HD];
  __shared__ float Lns[NLM];
  const u16* Kp = QKV + (size_t)NTOK*EMB + (size_t)b*SEQL*EMB + h*HD;
  {
    const int l = tid >> 2, p = tid & 3;        // each thread: 16 u16
    const int row = lidx[l];
    const u16* src = Kp + (size_t)row*EMB + p*16;
    *(u32x4*)&Ls[l*64 + p*16]     = *(const u32x4*)src;
    *(u32x4*)&Ls[l*64 + p*16 + 8] = *(const u32x4*)(src + 8);
  }
  __syncthreads();
  if (tid < 64) {
    float s = 0;
    for (int d = 0; d < 64; ++d) { float v = bf2f(Ls[tid*64 + d]); s += v*v; }
    Lns[tid] = s;
  }
  __syncthreads();
  const float invt = 1.0f / tempp[0];
  for (int e = tid; e < 4096; e += 256) {
    const int i = e >> 6, j = e & 63;
    float dot = 0;
    for (int d = 0; d < 64; ++d) dot += bf2f(Ls[i*64 + d]) * bf2f(Ls[j*64 + d]);
    const float c = fmaxf(Lns[i] + Lns[j] - 2.0f*dot, 0.0f);
    wker[(size_t)bh*4096 + e] = __expf(-c * invt) + (i == j ? 1e-6f : 0.0f);
  }
  for (int e = tid; e < 4096; e += 256) land[(size_t)bh*4096 + e] = Ls[e];
  if (tid < 64) lnorm[bh*64 + tid] = Lns[tid];
}

// ---------------- register-resident 64x64 Gauss-Jordan inversion ----------------
// One wave per (b,h). Column-per-lane, row-per-VGPR, fully unrolled so all
// register indices are compile-time. No LDS, no barriers. In-place over wker
// (full register load precedes any store; regenerated by k_land every call).
__global__ __launch_bounds__(64) void k_inv(float* __restrict__ wker)
{
  const int bh = blockIdx.x;
  const int lane = threadIdx.x;
  float* wp = wker + (size_t)bh * 4096;
  float w[64];
  #pragma unroll
  for (int r = 0; r < 64; ++r) w[r] = wp[r*64 + lane];
  #pragma unroll
  for (int cp = 0; cp < 64; ++cp) {
    const float diag = rdlane(w[cp], cp);
    const float inv  = 1.0f / diag;
    const float oneh = (lane == cp) ? 1.0f : 0.0f;
    // pj on lane j!=cp: W[cp][j]*inv ; on lane cp: 1+inv (makes the rank-1
    // update produce -f*inv in the pivot column)
    const float pj = w[cp] * inv + oneh * inv;
    #pragma unroll
    for (int r = 0; r < 64; ++r) {
      if (r == cp) continue;
      const float f = rdlane(w[r], cp);     // old W[r][cp], wave-uniform
      w[r] -= f * pj;
    }
    w[cp] = pj - oneh;                      // pivot row: W[cp][j]*inv, diag=inv
  }
  #pragma unroll
  for (int r = 0; r < 64; ++r) wp[r*64 + lane] = w[r];
}

// ---------------- reduce ZP/SP + apply Winv -> Y^T (bf16, 80x64) ----------------
__global__ __launch_bounds__(256) void k_apply(
    const float* __restrict__ winv, const float* __restrict__ ZP,
    const float* __restrict__ SP, u16* __restrict__ YT)
{
  const int bh = blockIdx.x;
  const int tid = threadIdx.x;
  __shared__ float Wi[64][65];
  __shared__ float Rh[64][66];
  for (int e = tid; e < 4096; e += 256) Wi[e >> 6][e & 63] = winv[(size_t)bh*4096 + e];
  for (int e = tid; e < 4096; e += 256) {
    float s = 0;
    #pragma unroll
    for (int c = 0; c < 8; ++c) s += ZP[((size_t)bh*8 + c)*4096 + e];
    Rh[e >> 6][e & 63] = s;
  }
  if (tid < 64) {
    float s = 0;
    #pragma unroll
    for (int c = 0; c < 8; ++c) s += SP[(bh*8 + c)*64 + tid];
    Rh[tid][64] = s;
  }
  __syncthreads();
  u16* yt = YT + (size_t)bh * 80 * 64;
  const int l = tid & 63, de0 = tid >> 6;
  for (int de = de0; de < 65; de += 4) {       // wave-uniform de -> Rh broadcast
    float s = 0;
    #pragma unroll
    for (int k = 0; k < 64; ++k) s += Wi[l][k] * Rh[k][de];
    yt[de*64 + l] = f2bf(s);
  }
  for (int e = tid; e < 15*64; e += 256) yt[65*64 + e] = 0;
}

// ---------------- Phi_K on the fly -> partial Z and column sums ----------------
__global__ __launch_bounds__(256) void k_phik(
    const u16* __restrict__ QKV, const u16* __restrict__ land,
    const float* __restrict__ lnorm, const float* __restrict__ tempp,
    float* __restrict__ ZP, float* __restrict__ SP)
{
  const int chunk = blockIdx.x;         // 0..7 (1024 rows each)
  const int bh = blockIdx.y;            // 0..31
  const int b = bh >> 4, h = bh & 15;
  const int tid = threadIdx.x, lane = tid & 63, wv = tid >> 6;
  const int fr = lane & 15, fk = (lane >> 4) * 8, rgrp = (lane >> 4) * 4;
  __shared__ __align__(16) u16 Ls[NLM*HD];
  __shared__ float Lns[NLM];
  __shared__ __align__(16) u16 phiT[4][NLM*32];   // per-wave [l][n32]
  __shared__ float zbuf[NLM*HD];
  __shared__ float wsum[4][NLM];

  for (int i = tid; i < 512; i += 256)
    *(u32x4*)&Ls[i*8] = *(const u32x4*)&land[(size_t)bh*4096 + (size_t)i*8];
  if (tid < 64) Lns[tid] = lnorm[bh*64 + tid];
  __syncthreads();

  const float invt = 1.0f / tempp[0];
  const u16* Kp = QKV + (size_t)NTOK*EMB   + (size_t)b*SEQL*EMB + h*HD;
  const u16* Vp = QKV + (size_t)2*NTOK*EMB + (size_t)b*SEQL*EMB + h*HD;

  u16x8 bl[2][4];
  #pragma unroll
  for (int ks = 0; ks < 2; ++ks)
    #pragma unroll
    for (int lt = 0; lt < 4; ++lt)
      bl[ks][lt] = ld8(&Ls[(lt*16 + fr)*64 + ks*32 + fk]);

  f32x4 zacc[4][4] = {};                 // [lt][dt]
  float pacc[4] = {0.f, 0.f, 0.f, 0.f};
  const int n0 = chunk*1024 + wv*256;

  for (int g = 0; g < 8; ++g) {          // 32 rows per group
    const int ng = n0 + g*32;
    u16x8 ak[2][2];
    #pragma unroll
    for (int rt = 0; rt < 2; ++rt)
      #pragma unroll
      for (int ks = 0; ks < 2; ++ks)
        ak[rt][ks] = ld8(Kp + (size_t)(ng + rt*16 + fr)*EMB + ks*32 + fk);
    float kn[2];
    #pragma unroll
    for (int rt = 0; rt < 2; ++rt) {
      float s = 0;
      #pragma unroll
      for (int ks = 0; ks < 2; ++ks)
        #pragma unroll
        for (int jj = 0; jj < 8; ++jj) { float v = bf2f(ak[rt][ks][jj]); s += v*v; }
      s += __shfl_xor(s, 16); s += __shfl_xor(s, 32);
      kn[rt] = s;
    }
    f32x4 ckl[2][4] = {};
    #pragma unroll
    for (int ks = 0; ks < 2; ++ks)
      #pragma unroll
      for (int rt = 0; rt < 2; ++rt)
        #pragma unroll
        for (int lt = 0; lt < 4; ++lt)
          ckl[rt][lt] = mfma16(ak[rt][ks], bl[ks][lt], ckl[rt][lt]);
    #pragma unroll
    for (int rt = 0; rt < 2; ++rt)
      #pragma unroll
      for (int lt = 0; lt < 4; ++lt)
        #pragma unroll
        for (int j = 0; j < 4; ++j) {
          const float knr = __shfl(kn[rt], rgrp + j);
          const float c = fmaxf(knr + Lns[lt*16 + fr] - 2.0f*ckl[rt][lt][j], 0.0f);
          const float ph = __expf(-c * invt);
          pacc[lt] += ph;
          phiT[wv][(lt*16 + fr)*32 + rt*16 + rgrp + j] = f2bf(ph);
        }
    u16x8 ap[4];
    #pragma unroll
    for (int lt = 0; lt < 4; ++lt) ap[lt] = ld8(&phiT[wv][(lt*16 + fr)*32 + fk]);
    #pragma unroll
    for (int dt = 0; dt < 4; ++dt) {
      u16x8 bvu;
      #pragma unroll
      for (int jj = 0; jj < 8; ++jj)
        bvu[jj] = Vp[(size_t)(ng + fk + jj)*EMB + dt*16 + fr];
      #pragma unroll
      for (int lt = 0; lt < 4; ++lt)
        zacc[lt][dt] = mfma16(ap[lt], bvu, zacc[lt][dt]);
    }
  }
  #pragma unroll
  for (int lt = 0; lt < 4; ++lt) {
    float s = pacc[lt];
    s += __shfl_xor(s, 16); s += __shfl_xor(s, 32);
    if (lane < 16) wsum[wv][lt*16 + lane] = s;
  }
  // deterministic cross-wave Z reduction
  for (int w = 0; w < 4; ++w) {
    __syncthreads();
    if (wv == w) {
      #pragma unroll
      for (int lt = 0; lt < 4; ++lt)
        #pragma unroll
        for (int dt = 0; dt < 4; ++dt)
          #pragma unroll
          for (int j = 0; j < 4; ++j) {
            const int l = lt*16 + rgrp + j, d = dt*16 + fr;
            if (w == 0) zbuf[l*64 + d]  = zacc[lt][dt][j];
            else        zbuf[l*64 + d] += zacc[lt][dt][j];
          }
    }
  }
  __syncthreads();
  float* zp = ZP + ((size_t)bh*8 + chunk)*4096;
  for (int e = tid; e < 4096; e += 256) zp[e] = zbuf[e];
  if (tid < 64)
    SP[(bh*8 + chunk)*64 + tid] = wsum[0][tid] + wsum[1][tid] + wsum[2][tid] + wsum[3][tid];
}

// ---------------- Phi_Q on the fly -> attn = (Phi_Q Y) / (Phi_Q y2) ----------------
__global__ __launch_bounds__(256) void k_out_attn(
    const u16* __restrict__ QKV, const u16* __restrict__ land,
    const float* __restrict__ lnorm, const float* __restrict__ tempp,
    const u16* __restrict__ YT, u16* __restrict__ attn)
{
  const int chunk = blockIdx.x;         // 0..63 (128 rows each)
  const int bh = blockIdx.y;
  const int b = bh >> 4, h = bh & 15;
  const int tid = threadIdx.x, lane = tid & 63, wv = tid >> 6;
  const int fr = lane & 15, fk = (lane >> 4) * 8, rgrp = (lane >> 4) * 4;
  __shared__ __align__(16) u16 Ls[NLM*HD];
  __shared__ float Lns[NLM];
  __shared__ __align__(16) u16 YTs[80*64];
  __shared__ __align__(16) u16 phin[4][32*64];

  for (int i = tid; i < 512; i += 256)
    *(u32x4*)&Ls[i*8] = *(const u32x4*)&land[(size_t)bh*4096 + (size_t)i*8];
  for (int i = tid; i < 640; i += 256)
    *(u32x4*)&YTs[i*8] = *(const u32x4*)&YT[(size_t)bh*5120 + (size_t)i*8];
  if (tid < 64) Lns[tid] = lnorm[bh*64 + tid];
  __syncthreads();

  const float invt = 1.0f / tempp[0];
  u16x8 bl[2][4], byf[2][5];
  #pragma unroll
  for (int ks = 0; ks < 2; ++ks) {
    #pragma unroll
    for (int lt = 0; lt < 4; ++lt) bl[ks][lt] = ld8(&Ls[(lt*16 + fr)*64 + ks*32 + fk]);
    #pragma unroll
    for (int dt = 0; dt < 5; ++dt) byf[ks][dt] = ld8(&YTs[(dt*16 + fr)*64 + ks*32 + fk]);
  }
  const u16* Qp = QKV + (size_t)b*SEQL*EMB + h*HD;
  const int n0 = chunk*128 + wv*32;
  u16x8 aq[2][2];
  #pragma unroll
  for (int rt = 0; rt < 2; ++rt)
    #pragma unroll
    for (int ks = 0; ks < 2; ++ks)
      aq[rt][ks] = ld8(Qp + (size_t)(n0 + rt*16 + fr)*EMB + ks*32 + fk);
  float qn[2];
  #pragma unroll
  for (int rt = 0; rt < 2; ++rt) {
    float s = 0;
    #pragma unroll
    for (int ks = 0; ks < 2; ++ks)
      #pragma unroll
      for (int jj = 0; jj < 8; ++jj) { float v = bf2f(aq[rt][ks][jj]); s += v*v; }
    s += __shfl_xor(s, 16); s += __shfl_xor(s, 32);
    qn[rt] = s;
  }
  f32x4 cql[2][4] = {};
  #pragma unroll
  for (int ks = 0; ks < 2; ++ks)
    #pragma unroll
    for (int rt = 0; rt < 2; ++rt)
      #pragma unroll
      for (int lt = 0; lt < 4; ++lt)
        cql[rt][lt] = mfma16(aq[rt][ks], bl[ks][lt], cql[rt][lt]);
  #pragma unroll
  for (int rt = 0; rt < 2; ++rt)
    #pragma unroll
    for (int lt = 0; lt < 4; ++lt)
      #pragma unroll
      for (int j = 0; j < 4; ++j) {
        const float knr = __shfl(qn[rt], rgrp + j);
        const float c = fmaxf(knr + Lns[lt*16 + fr] - 2.0f*cql[rt][lt][j], 0.0f);
        phin[wv][(rt*16 + rgrp + j)*64 + lt*16 + fr] = f2bf(__expf(-c * invt));
      }
  u16x8 ap[2][2];
  #pragma unroll
  for (int rt = 0; rt < 2; ++rt)
    #pragma unroll
    for (int ks = 0; ks < 2; ++ks)
      ap[rt][ks] = ld8(&phin[wv][(rt*16 + fr)*64 + ks*32 + fk]);
  f32x4 o[2][5] = {};
  #pragma unroll
  for (int ks = 0; ks < 2; ++ks)
    #pragma unroll
    for (int rt = 0; rt < 2; ++rt)
      #pragma unroll
      for (int dt = 0; dt < 5; ++dt)
        o[rt][dt] = mfma16(ap[rt][ks], byf[ks][dt], o[rt][dt]);
  u16* Apt = attn + (size_t)b*SEQL*EMB + h*HD;
  #pragma unroll
  for (int rt = 0; rt < 2; ++rt)
    #pragma unroll
    for (int j = 0; j < 4; ++j) {
      const float nv = fmaxf(__shfl(o[rt][4][j], lane & 48), 1e-10f);
      const float rn = 1.0f / nv;
      const int row = n0 + rt*16 + rgrp + j;
      #pragma unroll
      for (int dt = 0; dt < 4; ++dt)
        Apt[(size_t)row*EMB + dt*16 + fr] = f2bf(o[rt][dt][j] * rn);
    }
}

} // namespace

extern "C" void kernel_launch(void* const* d_in, const int* in_sizes, int n_in,
                              void* d_out, int out_size, void* d_ws, size_t ws_size,
                              hipStream_t stream) {
  (void)in_sizes; (void)n_in; (void)out_size; (void)ws_size;
  const float* query = (const float*)d_in[0];
  const float* Wq = (const float*)d_in[1];
  const float* bq = (const float*)d_in[2];
  const float* Wk = (const float*)d_in[3];
  const float* bk = (const float*)d_in[4];
  const float* Wv = (const float*)d_in[5];
  const float* bv = (const float*)d_in[6];
  const float* Wo = (const float*)d_in[7];
  const float* bo = (const float*)d_in[8];
  const float* temp = (const float*)d_in[9];
  const int*   lidx = (const int*)d_in[10];
  float* out = (float*)d_out;
  char* ws = (char*)d_ws;

  u16* qbf   = (u16*)(ws + OFF_QBF);
  u16* wbf   = (u16*)(ws + OFF_WBF);
  u16* qkv   = (u16*)(ws + OFF_QKV);
  u16* attn  = (u16*)(ws + OFF_ATT);
  u16* land  = (u16*)(ws + OFF_LAND);
  float* lnorm = (float*)(ws + OFF_LN);
  float* wker  = (float*)(ws + OFF_WK);
  float* ZP  = (float*)(ws + OFF_ZP);
  float* SP  = (float*)(ws + OFF_SP);
  u16* YT    = (u16*)(ws + OFF_YT);

  k_cvt<<<NTOK*EMB/8/256, 256, 0, stream>>>(query, qbf, NTOK*EMB/8);
  k_cvt<<<EMB*EMB/8/256, 256, 0, stream>>>(Wq, wbf + 0*EMB*EMB, EMB*EMB/8);
  k_cvt<<<EMB*EMB/8/256, 256, 0, stream>>>(Wk, wbf + 1*EMB*EMB, EMB*EMB/8);
  k_cvt<<<EMB*EMB/8/256, 256, 0, stream>>>(Wv, wbf + 2*EMB*EMB, EMB*EMB/8);
  k_cvt<<<EMB*EMB/8/256, 256, 0, stream>>>(Wo, wbf + 3*EMB*EMB, EMB*EMB/8);

  k_gemm256<0><<<dim3(12, 64), 512, 0, stream>>>(qbf, wbf, bq, bk, bv, qkv, nullptr);
  k_land<<<32, 256, 0, stream>>>(qkv, lidx, temp, land, lnorm, wker);
  k_inv<<<32, 64, 0, stream>>>(wker);                 // wker -> Winv in place
  k_phik<<<dim3(8, 32), 256, 0, stream>>>(qkv, land, lnorm, temp, ZP, SP);
  k_apply<<<32, 256, 0, stream>>>(wker, ZP, SP, YT);
  k_out_attn<<<dim3(64, 32), 256, 0, stream>>>(qkv, land, lnorm, temp, YT, attn);
  k_gemm256<1><<<dim3(4, 64), 512, 0, stream>>>(attn, wbf + 3*EMB*EMB, bo, nullptr,
                                                nullptr, nullptr, out);
}

// Round 6
// 283.333 us; speedup vs baseline: 2.0214x; 2.0214x over previous
//
#include <hip/hip_runtime.h>
#include <stdint.h>

typedef unsigned short u16;
typedef unsigned int u32;
typedef __attribute__((ext_vector_type(8))) __bf16 bf16x8;
typedef __attribute__((ext_vector_type(8))) u16 u16x8;
typedef __attribute__((ext_vector_type(4))) float f32x4;
typedef __attribute__((ext_vector_type(4))) u32 u32x4;

#define DEV static __device__ __forceinline__

namespace {

constexpr int NB2  = 2;
constexpr int SEQL = 8192;
constexpr int EMB  = 1024;
constexpr int HD   = 64;
constexpr int NLM  = 64;
constexpr int NTOK = NB2 * SEQL;   // 16384

// workspace layout (bytes)
constexpr size_t OFF_QBF  = 0;                          // query bf16   33554432
constexpr size_t OFF_WBF  = OFF_QBF  + 33554432;        // 4 weights    8388608
constexpr size_t OFF_QKV  = OFF_WBF  + 8388608;         // Q,K,V bf16   100663296
constexpr size_t OFF_ATT  = OFF_QKV  + 100663296;       // attn bf16    33554432
constexpr size_t OFF_LAND = OFF_ATT  + 33554432;        // landmarks    262144
constexpr size_t OFF_LN   = OFF_LAND + 262144;          // |l|^2 f32    8192
constexpr size_t OFF_WK   = OFF_LN   + 8192;            // W kernel f32 -> Winv (in-place) 524288
constexpr size_t OFF_ZP   = OFF_WK   + 524288;          // Z partials   4194304
constexpr size_t OFF_SP   = OFF_ZP   + 4194304;         // sum partials 65536
constexpr size_t OFF_YT   = OFF_SP   + 65536;           // Y^T bf16     327680

DEV u16 f2bf(float f){
  u32 u = __builtin_bit_cast(u32, f);
  u32 r = (u + 0x7FFFu + ((u >> 16) & 1u)) >> 16;
  return (u16)r;
}
DEV float bf2f(u16 h){ u32 u = ((u32)h) << 16; return __builtin_bit_cast(float, u); }
DEV u16x8 ld8(const u16* p){ return *(const u16x8*)p; }
DEV f32x4 mfma16(u16x8 a, u16x8 b, f32x4 c){
  return __builtin_amdgcn_mfma_f32_16x16x32_bf16(
      __builtin_bit_cast(bf16x8, a), __builtin_bit_cast(bf16x8, b), c, 0, 0, 0);
}
// async global->LDS, 16B per lane; LDS dest is wave-uniform base + lane*16.
DEV void gld_lds16(void* lds, const void* g){
  __builtin_amdgcn_global_load_lds(
      (__attribute__((address_space(1))) void*)(uintptr_t)g,
      (__attribute__((address_space(3))) void*)(u32)(uintptr_t)lds,
      16, 0, 0);
}
DEV void vmwait4(){ asm volatile("s_waitcnt vmcnt(4)" ::: "memory"); }
DEV void vmwait0(){ asm volatile("s_waitcnt vmcnt(0)" ::: "memory"); }
DEV void barrier_pin(){
  __builtin_amdgcn_s_barrier();
  __builtin_amdgcn_sched_barrier(0);
}
// LDS physical<->logical byte permutation within a 16KB half-tile:
// rows are 128B (=32 banks), so fr contributes 0 bank spread; XOR the
// 16B-slot index (bits 4-6) with row bits 0-2 (bits 7-9). Involution.
DEV u32 swz(u32 a){ return a ^ (((a >> 7) & 7u) << 4); }
DEV float rdlane(float v, int l){
  return __builtin_bit_cast(float, __builtin_amdgcn_readlane(__builtin_bit_cast(int, v), l));
}

// ---------------- fp32 -> bf16 pack ----------------
__global__ __launch_bounds__(256) void k_cvt(const float* __restrict__ src,
                                             u16* __restrict__ dst, int n8){
  int i = blockIdx.x * blockDim.x + threadIdx.x;
  if (i >= n8) return;
  float t[8];
  *(float4*)&t[0] = ((const float4*)src)[2*i];
  *(float4*)&t[4] = ((const float4*)src)[2*i + 1];
  u16x8 o;
  #pragma unroll
  for (int j = 0; j < 8; ++j) o[j] = f2bf(t[j]);
  *(u16x8*)&dst[(size_t)i * 8] = o;
}

// ---------------- 256x256 8-phase GEMM (m201-style template) ----------------
// C[m][n] = sum_k A[m][k] * W[n][k] (+bias). BK=64, 2 K-tiles/iter, 8 waves.
// MODE 0: fused QKV (3 weight mats, bf16 out). MODE 1: out-proj (f32 out).
template <int MODE>
__global__ __launch_bounds__(512, 2) void k_gemm256(
    const u16* __restrict__ A, const u16* __restrict__ Wb,
    const float* __restrict__ b0, const float* __restrict__ b1,
    const float* __restrict__ b2, u16* __restrict__ OutB, float* __restrict__ OutF)
{
  constexpr int NI = 8;                       // iterations (2 K-tiles each), K=1024
  __shared__ __align__(16) u16 lds[2][2][2][128*64];   // [buf][mat][half][row*64+k]
  const int tid = threadIdx.x, lane = tid & 63, wv = tid >> 6;
  const int wr = wv >> 2, wc = wv & 3;        // 2 x 4 wave grid
  const int fr = lane & 15, fk = (lane >> 4) * 8;

  constexpr int NBX = (MODE == 0) ? 12 : 4;
  constexpr int CPX = NBX * 64 / 8;           // blocks per XCD chunk
  const int lin = blockIdx.x + NBX * blockIdx.y;
  const int w = (lin & 7) * CPX + (lin >> 3); // bijective XCD chunk swizzle
  const int bxw = w % NBX, byw = w / NBX;
  const int wsel = (MODE == 0) ? (bxw >> 2) : 0;
  const int col0 = (MODE == 0) ? ((bxw & 3) * 256) : (bxw * 256);
  const int row0 = byw * 256;
  const u16* Bm = Wb + (size_t)wsel * EMB * EMB;

  // staging: linear LDS dest byte P holds logical byte swz(P)
  int voff[2]; u32 lo_[2];
  #pragma unroll
  for (int j = 0; j < 2; ++j) {
    u32 P  = (u32)((j*8 + wv) * 1024);
    u32 Pl = P + (u32)lane * 16;
    u32 L  = swz(Pl);
    voff[j] = (int)((L >> 7) * EMB + ((L >> 1) & 63));
    lo_[j]  = P;
  }
  // swizzled per-lane ds_read byte offsets (row = fr within each 16-row stripe)
  u32 qsw[2];
  #pragma unroll
  for (int ks = 0; ks < 2; ++ks)
    qsw[ks] = swz((u32)(fr*128 + ks*64 + fk*2));

  f32x4 acc[8][4] = {};
  u16x8 af[2][8], bfr[2][4];

  auto STAGE = [&](int buf, int mat, int half, int kt) {
    const u16* gb = (mat == 0)
      ? (A  + (size_t)(row0 + half*128) * EMB + kt*64)
      : (Bm + (size_t)(col0 + half*128) * EMB + kt*64);
    char* lb = (char*)&lds[buf][mat][half][0];
    #pragma unroll
    for (int j = 0; j < 2; ++j)
      gld_lds16(lb + lo_[j], gb + voff[j]);
  };
  auto LDA = [&](int buf, int m, int ks) -> u16x8 {
    return ld8((const u16*)((const char*)&lds[buf][0][wr][0] + m*2048 + qsw[ks]));
  };
  auto LDB = [&](int buf, int n, int ks) -> u16x8 {
    return ld8((const u16*)((const char*)&lds[buf][1][wc>>1][0]
                            + (wc&1)*8192 + n*2048 + qsw[ks]));
  };
  auto READ_LO = [&](int buf) {       // A m0-3 + B n0-1 (both ks): 12 ds_read_b128
    #pragma unroll
    for (int ks = 0; ks < 2; ++ks) {
      #pragma unroll
      for (int m = 0; m < 4; ++m) af[ks][m] = LDA(buf, m, ks);
      #pragma unroll
      for (int n = 0; n < 2; ++n) bfr[ks][n] = LDB(buf, n, ks);
    }
  };
  auto READ_HI = [&](int buf) {       // A m4-7 + B n2-3
    #pragma unroll
    for (int ks = 0; ks < 2; ++ks) {
      #pragma unroll
      for (int m = 0; m < 4; ++m) af[ks][4+m] = LDA(buf, 4+m, ks);
      #pragma unroll
      for (int n = 0; n < 2; ++n) bfr[ks][2+n] = LDB(buf, 2+n, ks);
    }
  };
  auto MFMAQ = [&](int mh, int nh) {  // one C-quadrant x K=64: 16 MFMA
    __builtin_amdgcn_s_setprio(1);
    #pragma unroll
    for (int ks = 0; ks < 2; ++ks)
      #pragma unroll
      for (int m = 0; m < 4; ++m)
        #pragma unroll
        for (int n = 0; n < 2; ++n) {
          const int mi = mh*4 + m, ni = nh*2 + n;
          acc[mi][ni] = mfma16(af[ks][mi], bfr[ks][ni], acc[mi][ni]);
        }
    __builtin_amdgcn_s_setprio(0);
  };

  // prologue: K0 full -> buf0; K1.A0,A1 -> buf1; wait K0 landed
  STAGE(0,0,0,0); STAGE(0,0,1,0); STAGE(0,1,0,0); STAGE(0,1,1,0);
  STAGE(1,0,0,1); STAGE(1,0,1,1);
  vmwait4();
  barrier_pin();

  #pragma unroll 1
  for (int it = 0; it < NI; ++it) {
    const int kt0 = 2*it;
    const bool last = (it == NI-1);
    // ph1: reads buf0 lo; stage (kt0+1).B0 -> buf1
    READ_LO(0); STAGE(1,1,0,kt0+1);
    barrier_pin(); MFMAQ(0,0); barrier_pin();
    // ph2: reads buf0 hi; stage (kt0+1).B1 -> buf1
    READ_HI(0); STAGE(1,1,1,kt0+1);
    barrier_pin(); MFMAQ(0,1); barrier_pin();
    // ph3: stage (kt0+2).A0 -> buf0 (buf0 fully read after ph2)
    if (!last) STAGE(0,0,0,kt0+2);
    barrier_pin(); MFMAQ(1,1); barrier_pin();
    // ph4: stage (kt0+2).A1; counted wait -> buf1 (kt0+1) fully landed
    if (!last) { STAGE(0,0,1,kt0+2); vmwait4(); } else { vmwait0(); }
    barrier_pin(); MFMAQ(1,0); barrier_pin();
    // ph5: reads buf1 lo; stage (kt0+2).B0 -> buf0
    READ_LO(1); if (!last) STAGE(0,1,0,kt0+2);
    barrier_pin(); MFMAQ(0,0); barrier_pin();
    // ph6: reads buf1 hi; stage (kt0+2).B1 -> buf0
    READ_HI(1); if (!last) STAGE(0,1,1,kt0+2);
    barrier_pin(); MFMAQ(0,1); barrier_pin();
    // ph7: stage (kt0+3).A0 -> buf1 (buf1 fully read after ph6)
    if (!last) STAGE(1,0,0,kt0+3);
    barrier_pin(); MFMAQ(1,1); barrier_pin();
    // ph8: stage (kt0+3).A1; counted wait -> buf0 (kt0+2) fully landed
    if (!last) { STAGE(1,0,1,kt0+3); vmwait4(); }
    barrier_pin(); MFMAQ(1,0); barrier_pin();
  }

  // epilogue
  const int rgrp = (lane >> 4) * 4;
  if (MODE == 0) {
    const float* bias = (wsel == 0) ? b0 : ((wsel == 1) ? b1 : b2);
    u16* Out = OutB + (size_t)wsel * NTOK * EMB;
    #pragma unroll
    for (int m = 0; m < 8; ++m) {
      const int r0 = row0 + wr*128 + m*16 + rgrp;
      #pragma unroll
      for (int n = 0; n < 4; ++n) {
        const int c = col0 + wc*64 + n*16 + fr;
        const float bb = bias[c];
        #pragma unroll
        for (int j = 0; j < 4; ++j)
          Out[(size_t)(r0 + j)*EMB + c] = f2bf(acc[m][n][j] + bb);
      }
    }
  } else {
    #pragma unroll
    for (int m = 0; m < 8; ++m) {
      const int r0 = row0 + wr*128 + m*16 + rgrp;
      #pragma unroll
      for (int n = 0; n < 4; ++n) {
        const int c = col0 + wc*64 + n*16 + fr;
        const float bb = b0[c];
        #pragma unroll
        for (int j = 0; j < 4; ++j)
          OutF[(size_t)(r0 + j)*EMB + c] = acc[m][n][j] + bb;
      }
    }
  }
}

// ---------------- landmarks: gather, norms, W kernel ----------------
__global__ __launch_bounds__(256) void k_land(
    const u16* __restrict__ QKV, const int* __restrict__ lidx,
    const float* __restrict__ tempp,
    u16* __restrict__ land, float* __restrict__ lnorm, float* __restrict__ wker)
{
  const int bh = blockIdx.x;            // 0..31
  const int b = bh >> 4, h = bh & 15;
  const int tid = threadIdx.x;
  __shared__ __align__(16) u16 Ls[NLM*HD];
  __shared__ float Lns[NLM];
  const u16* Kp = QKV + (size_t)NTOK*EMB + (size_t)b*SEQL*EMB + h*HD;
  {
    const int l = tid >> 2, p = tid & 3;        // each thread: 16 u16
    const int row = lidx[l];
    const u16* src = Kp + (size_t)row*EMB + p*16;
    *(u32x4*)&Ls[l*64 + p*16]     = *(const u32x4*)src;
    *(u32x4*)&Ls[l*64 + p*16 + 8] = *(const u32x4*)(src + 8);
  }
  __syncthreads();
  if (tid < 64) {
    float s = 0;
    for (int d = 0; d < 64; ++d) { float v = bf2f(Ls[tid*64 + d]); s += v*v; }
    Lns[tid] = s;
  }
  __syncthreads();
  const float invt = 1.0f / tempp[0];
  for (int e = tid; e < 4096; e += 256) {
    const int i = e >> 6, j = e & 63;
    float dot = 0;
    for (int d = 0; d < 64; ++d) dot += bf2f(Ls[i*64 + d]) * bf2f(Ls[j*64 + d]);
    const float c = fmaxf(Lns[i] + Lns[j] - 2.0f*dot, 0.0f);
    wker[(size_t)bh*4096 + e] = __expf(-c * invt) + (i == j ? 1e-6f : 0.0f);
  }
  for (int e = tid; e < 4096; e += 256) land[(size_t)bh*4096 + e] = Ls[e];
  if (tid < 64) lnorm[bh*64 + tid] = Lns[tid];
}

// ---------------- register-resident 64x64 Gauss-Jordan inversion ----------------
// One wave per (b,h). Column-per-lane, row-per-VGPR. Runtime pivot loop
// (#pragma unroll 1: ~1KB body, icache-resident) with ROW ROTATION so all
// register indices are compile-time: at iter cp, physical w[0] == logical
// row cp; update w[r-1] = w[r] - f*pj shifts rows down; new pivot row ->
// w[63]. After 64 iters rotation is identity. Same arithmetic as R5 (verified).
__global__ __launch_bounds__(64) void k_inv(float* __restrict__ wker)
{
  const int bh = blockIdx.x;
  const int lane = threadIdx.x;
  float* wp = wker + (size_t)bh * 4096;
  float w[64];
  #pragma unroll
  for (int r = 0; r < 64; ++r) w[r] = wp[r*64 + lane];
  #pragma unroll 1
  for (int cp = 0; cp < 64; ++cp) {
    const float diag = rdlane(w[0], cp);
    const float inv  = 1.0f / diag;
    const float oneh = (lane == cp) ? 1.0f : 0.0f;
    // pj on lane j!=cp: W[cp][j]*inv ; on lane cp: 1+inv (rank-1 update then
    // yields -f*inv in the pivot column)
    const float pj = w[0] * inv + oneh * inv;
    const float newpiv = pj - oneh;       // pivot row: W[cp][j]*inv, diag=inv
    #pragma unroll
    for (int r = 1; r < 64; ++r) {
      const float f = rdlane(w[r], cp);   // old W[logical r][cp], wave-uniform
      w[r-1] = w[r] - f * pj;
    }
    w[63] = newpiv;
  }
  #pragma unroll
  for (int r = 0; r < 64; ++r) wp[r*64 + lane] = w[r];
}

// ---------------- reduce ZP/SP + apply Winv -> Y^T (bf16, 80x64) ----------------
__global__ __launch_bounds__(256) void k_apply(
    const float* __restrict__ winv, const float* __restrict__ ZP,
    const float* __restrict__ SP, u16* __restrict__ YT)
{
  const int bh = blockIdx.x;
  const int tid = threadIdx.x;
  __shared__ float Wi[64][65];
  __shared__ float Rh[64][66];
  for (int e = tid; e < 4096; e += 256) Wi[e >> 6][e & 63] = winv[(size_t)bh*4096 + e];
  for (int e = tid; e < 4096; e += 256) {
    float s = 0;
    #pragma unroll
    for (int c = 0; c < 8; ++c) s += ZP[((size_t)bh*8 + c)*4096 + e];
    Rh[e >> 6][e & 63] = s;
  }
  if (tid < 64) {
    float s = 0;
    #pragma unroll
    for (int c = 0; c < 8; ++c) s += SP[(bh*8 + c)*64 + tid];
    Rh[tid][64] = s;
  }
  __syncthreads();
  u16* yt = YT + (size_t)bh * 80 * 64;
  const int l = tid & 63, de0 = tid >> 6;
  for (int de = de0; de < 65; de += 4) {       // wave-uniform de -> Rh broadcast
    float s = 0;
    #pragma unroll
    for (int k = 0; k < 64; ++k) s += Wi[l][k] * Rh[k][de];
    yt[de*64 + l] = f2bf(s);
  }
  for (int e = tid; e < 15*64; e += 256) yt[65*64 + e] = 0;
}

// ---------------- Phi_K on the fly -> partial Z and column sums ----------------
__global__ __launch_bounds__(256) void k_phik(
    const u16* __restrict__ QKV, const u16* __restrict__ land,
    const float* __restrict__ lnorm, const float* __restrict__ tempp,
    float* __restrict__ ZP, float* __restrict__ SP)
{
  const int chunk = blockIdx.x;         // 0..7 (1024 rows each)
  const int bh = blockIdx.y;            // 0..31
  const int b = bh >> 4, h = bh & 15;
  const int tid = threadIdx.x, lane = tid & 63, wv = tid >> 6;
  const int fr = lane & 15, fk = (lane >> 4) * 8, rgrp = (lane >> 4) * 4;
  __shared__ __align__(16) u16 Ls[NLM*HD];
  __shared__ float Lns[NLM];
  __shared__ __align__(16) u16 phiT[4][NLM*32];   // per-wave [l][n32]
  __shared__ float zbuf[NLM*HD];
  __shared__ float wsum[4][NLM];

  for (int i = tid; i < 512; i += 256)
    *(u32x4*)&Ls[i*8] = *(const u32x4*)&land[(size_t)bh*4096 + (size_t)i*8];
  if (tid < 64) Lns[tid] = lnorm[bh*64 + tid];
  __syncthreads();

  const float invt = 1.0f / tempp[0];
  const u16* Kp = QKV + (size_t)NTOK*EMB   + (size_t)b*SEQL*EMB + h*HD;
  const u16* Vp = QKV + (size_t)2*NTOK*EMB + (size_t)b*SEQL*EMB + h*HD;

  u16x8 bl[2][4];
  #pragma unroll
  for (int ks = 0; ks < 2; ++ks)
    #pragma unroll
    for (int lt = 0; lt < 4; ++lt)
      bl[ks][lt] = ld8(&Ls[(lt*16 + fr)*64 + ks*32 + fk]);

  f32x4 zacc[4][4] = {};                 // [lt][dt]
  float pacc[4] = {0.f, 0.f, 0.f, 0.f};
  const int n0 = chunk*1024 + wv*256;

  for (int g = 0; g < 8; ++g) {          // 32 rows per group
    const int ng = n0 + g*32;
    u16x8 ak[2][2];
    #pragma unroll
    for (int rt = 0; rt < 2; ++rt)
      #pragma unroll
      for (int ks = 0; ks < 2; ++ks)
        ak[rt][ks] = ld8(Kp + (size_t)(ng + rt*16 + fr)*EMB + ks*32 + fk);
    float kn[2];
    #pragma unroll
    for (int rt = 0; rt < 2; ++rt) {
      float s = 0;
      #pragma unroll
      for (int ks = 0; ks < 2; ++ks)
        #pragma unroll
        for (int jj = 0; jj < 8; ++jj) { float v = bf2f(ak[rt][ks][jj]); s += v*v; }
      s += __shfl_xor(s, 16); s += __shfl_xor(s, 32);
      kn[rt] = s;
    }
    f32x4 ckl[2][4] = {};
    #pragma unroll
    for (int ks = 0; ks < 2; ++ks)
      #pragma unroll
      for (int rt = 0; rt < 2; ++rt)
        #pragma unroll
        for (int lt = 0; lt < 4; ++lt)
          ckl[rt][lt] = mfma16(ak[rt][ks], bl[ks][lt], ckl[rt][lt]);
    #pragma unroll
    for (int rt = 0; rt < 2; ++rt)
      #pragma unroll
      for (int lt = 0; lt < 4; ++lt)
        #pragma unroll
        for (int j = 0; j < 4; ++j) {
          const float knr = __shfl(kn[rt], rgrp + j);
          const float c = fmaxf(knr + Lns[lt*16 + fr] - 2.0f*ckl[rt][lt][j], 0.0f);
          const float ph = __expf(-c * invt);
          pacc[lt] += ph;
          phiT[wv][(lt*16 + fr)*32 + rt*16 + rgrp + j] = f2bf(ph);
        }
    u16x8 ap[4];
    #pragma unroll
    for (int lt = 0; lt < 4; ++lt) ap[lt] = ld8(&phiT[wv][(lt*16 + fr)*32 + fk]);
    #pragma unroll
    for (int dt = 0; dt < 4; ++dt) {
      u16x8 bvu;
      #pragma unroll
      for (int jj = 0; jj < 8; ++jj)
        bvu[jj] = Vp[(size_t)(ng + fk + jj)*EMB + dt*16 + fr];
      #pragma unroll
      for (int lt = 0; lt < 4; ++lt)
        zacc[lt][dt] = mfma16(ap[lt], bvu, zacc[lt][dt]);
    }
  }
  #pragma unroll
  for (int lt = 0; lt < 4; ++lt) {
    float s = pacc[lt];
    s += __shfl_xor(s, 16); s += __shfl_xor(s, 32);
    if (lane < 16) wsum[wv][lt*16 + lane] = s;
  }
  // deterministic cross-wave Z reduction
  for (int w = 0; w < 4; ++w) {
    __syncthreads();
    if (wv == w) {
      #pragma unroll
      for (int lt = 0; lt < 4; ++lt)
        #pragma unroll
        for (int dt = 0; dt < 4; ++dt)
          #pragma unroll
          for (int j = 0; j < 4; ++j) {
            const int l = lt*16 + rgrp + j, d = dt*16 + fr;
            if (w == 0) zbuf[l*64 + d]  = zacc[lt][dt][j];
            else        zbuf[l*64 + d] += zacc[lt][dt][j];
          }
    }
  }
  __syncthreads();
  float* zp = ZP + ((size_t)bh*8 + chunk)*4096;
  for (int e = tid; e < 4096; e += 256) zp[e] = zbuf[e];
  if (tid < 64)
    SP[(bh*8 + chunk)*64 + tid] = wsum[0][tid] + wsum[1][tid] + wsum[2][tid] + wsum[3][tid];
}

// ---------------- Phi_Q on the fly -> attn = (Phi_Q Y) / (Phi_Q y2) ----------------
__global__ __launch_bounds__(256) void k_out_attn(
    const u16* __restrict__ QKV, const u16* __restrict__ land,
    const float* __restrict__ lnorm, const float* __restrict__ tempp,
    const u16* __restrict__ YT, u16* __restrict__ attn)
{
  const int chunk = blockIdx.x;         // 0..63 (128 rows each)
  const int bh = blockIdx.y;
  const int b = bh >> 4, h = bh & 15;
  const int tid = threadIdx.x, lane = tid & 63, wv = tid >> 6;
  const int fr = lane & 15, fk = (lane >> 4) * 8, rgrp = (lane >> 4) * 4;
  __shared__ __align__(16) u16 Ls[NLM*HD];
  __shared__ float Lns[NLM];
  __shared__ __align__(16) u16 YTs[80*64];
  __shared__ __align__(16) u16 phin[4][32*64];

  for (int i = tid; i < 512; i += 256)
    *(u32x4*)&Ls[i*8] = *(const u32x4*)&land[(size_t)bh*4096 + (size_t)i*8];
  for (int i = tid; i < 640; i += 256)
    *(u32x4*)&YTs[i*8] = *(const u32x4*)&YT[(size_t)bh*5120 + (size_t)i*8];
  if (tid < 64) Lns[tid] = lnorm[bh*64 + tid];
  __syncthreads();

  const float invt = 1.0f / tempp[0];
  u16x8 bl[2][4], byf[2][5];
  #pragma unroll
  for (int ks = 0; ks < 2; ++ks) {
    #pragma unroll
    for (int lt = 0; lt < 4; ++lt) bl[ks][lt] = ld8(&Ls[(lt*16 + fr)*64 + ks*32 + fk]);
    #pragma unroll
    for (int dt = 0; dt < 5; ++dt) byf[ks][dt] = ld8(&YTs[(dt*16 + fr)*64 + ks*32 + fk]);
  }
  const u16* Qp = QKV + (size_t)b*SEQL*EMB + h*HD;
  const int n0 = chunk*128 + wv*32;
  u16x8 aq[2][2];
  #pragma unroll
  for (int rt = 0; rt < 2; ++rt)
    #pragma unroll
    for (int ks = 0; ks < 2; ++ks)
      aq[rt][ks] = ld8(Qp + (size_t)(n0 + rt*16 + fr)*EMB + ks*32 + fk);
  float qn[2];
  #pragma unroll
  for (int rt = 0; rt < 2; ++rt) {
    float s = 0;
    #pragma unroll
    for (int ks = 0; ks < 2; ++ks)
      #pragma unroll
      for (int jj = 0; jj < 8; ++jj) { float v = bf2f(aq[rt][ks][jj]); s += v*v; }
    s += __shfl_xor(s, 16); s += __shfl_xor(s, 32);
    qn[rt] = s;
  }
  f32x4 cql[2][4] = {};
  #pragma unroll
  for (int ks = 0; ks < 2; ++ks)
    #pragma unroll
    for (int rt = 0; rt < 2; ++rt)
      #pragma unroll
      for (int lt = 0; lt < 4; ++lt)
        cql[rt][lt] = mfma16(aq[rt][ks], bl[ks][lt], cql[rt][lt]);
  #pragma unroll
  for (int rt = 0; rt < 2; ++rt)
    #pragma unroll
    for (int lt = 0; lt < 4; ++lt)
      #pragma unroll
      for (int j = 0; j < 4; ++j) {
        const float knr = __shfl(qn[rt], rgrp + j);
        const float c = fmaxf(knr + Lns[lt*16 + fr] - 2.0f*cql[rt][lt][j], 0.0f);
        phin[wv][(rt*16 + rgrp + j)*64 + lt*16 + fr] = f2bf(__expf(-c * invt));
      }
  u16x8 ap[2][2];
  #pragma unroll
  for (int rt = 0; rt < 2; ++rt)
    #pragma unroll
    for (int ks = 0; ks < 2; ++ks)
      ap[rt][ks] = ld8(&phin[wv][(rt*16 + fr)*64 + ks*32 + fk]);
  f32x4 o[2][5] = {};
  #pragma unroll
  for (int ks = 0; ks < 2; ++ks)
    #pragma unroll
    for (int rt = 0; rt < 2; ++rt)
      #pragma unroll
      for (int dt = 0; dt < 5; ++dt)
        o[rt][dt] = mfma16(ap[rt][ks], byf[ks][dt], o[rt][dt]);
  u16* Apt = attn + (size_t)b*SEQL*EMB + h*HD;
  #pragma unroll
  for (int rt = 0; rt < 2; ++rt)
    #pragma unroll
    for (int j = 0; j < 4; ++j) {
      const float nv = fmaxf(__shfl(o[rt][4][j], lane & 48), 1e-10f);
      const float rn = 1.0f / nv;
      const int row = n0 + rt*16 + rgrp + j;
      #pragma unroll
      for (int dt = 0; dt < 4; ++dt)
        Apt[(size_t)row*EMB + dt*16 + fr] = f2bf(o[rt][dt][j] * rn);
    }
}

} // namespace

extern "C" void kernel_launch(void* const* d_in, const int* in_sizes, int n_in,
                              void* d_out, int out_size, void* d_ws, size_t ws_size,
                              hipStream_t stream) {
  (void)in_sizes; (void)n_in; (void)out_size; (void)ws_size;
  const float* query = (const float*)d_in[0];
  const float* Wq = (const float*)d_in[1];
  const float* bq = (const float*)d_in[2];
  const float* Wk = (const float*)d_in[3];
  const float* bk = (const float*)d_in[4];
  const float* Wv = (const float*)d_in[5];
  const float* bv = (const float*)d_in[6];
  const float* Wo = (const float*)d_in[7];
  const float* bo = (const float*)d_in[8];
  const float* temp = (const float*)d_in[9];
  const int*   lidx = (const int*)d_in[10];
  float* out = (float*)d_out;
  char* ws = (char*)d_ws;

  u16* qbf   = (u16*)(ws + OFF_QBF);
  u16* wbf   = (u16*)(ws + OFF_WBF);
  u16* qkv   = (u16*)(ws + OFF_QKV);
  u16* attn  = (u16*)(ws + OFF_ATT);
  u16* land  = (u16*)(ws + OFF_LAND);
  float* lnorm = (float*)(ws + OFF_LN);
  float* wker  = (float*)(ws + OFF_WK);
  float* ZP  = (float*)(ws + OFF_ZP);
  float* SP  = (float*)(ws + OFF_SP);
  u16* YT    = (u16*)(ws + OFF_YT);

  k_cvt<<<NTOK*EMB/8/256, 256, 0, stream>>>(query, qbf, NTOK*EMB/8);
  k_cvt<<<EMB*EMB/8/256, 256, 0, stream>>>(Wq, wbf + 0*EMB*EMB, EMB*EMB/8);
  k_cvt<<<EMB*EMB/8/256, 256, 0, stream>>>(Wk, wbf + 1*EMB*EMB, EMB*EMB/8);
  k_cvt<<<EMB*EMB/8/256, 256, 0, stream>>>(Wv, wbf + 2*EMB*EMB, EMB*EMB/8);
  k_cvt<<<EMB*EMB/8/256, 256, 0, stream>>>(Wo, wbf + 3*EMB*EMB, EMB*EMB/8);

  k_gemm256<0><<<dim3(12, 64), 512, 0, stream>>>(qbf, wbf, bq, bk, bv, qkv, nullptr);
  k_land<<<32, 256, 0, stream>>>(qkv, lidx, temp, land, lnorm, wker);
  k_inv<<<32, 64, 0, stream>>>(wker);                 // wker -> Winv in place
  k_phik<<<dim3(8, 32), 256, 0, stream>>>(qkv, land, lnorm, temp, ZP, SP);
  k_apply<<<32, 256, 0, stream>>>(wker, ZP, SP, YT);
  k_out_attn<<<dim3(64, 32), 256, 0, stream>>>(qkv, land, lnorm, temp, YT, attn);
  k_gemm256<1><<<dim3(4, 64), 512, 0, stream>>>(attn, wbf + 3*EMB*EMB, bo, nullptr,
                                                nullptr, nullptr, out);
}

// Round 7
// 267.948 us; speedup vs baseline: 2.1375x; 1.0574x over previous
//
#include <hip/hip_runtime.h>
#include <stdint.h>

typedef unsigned short u16;
typedef unsigned int u32;
typedef __attribute__((ext_vector_type(8))) __bf16 bf16x8;
typedef __attribute__((ext_vector_type(8))) u16 u16x8;
typedef __attribute__((ext_vector_type(4))) float f32x4;
typedef __attribute__((ext_vector_type(4))) u32 u32x4;

#define DEV static __device__ __forceinline__

namespace {

constexpr int NB2  = 2;
constexpr int SEQL = 8192;
constexpr int EMB  = 1024;
constexpr int HD   = 64;
constexpr int NLM  = 64;
constexpr int NTOK = NB2 * SEQL;   // 16384

// workspace layout (bytes)
constexpr size_t OFF_QBF  = 0;                          // query bf16   33554432
constexpr size_t OFF_WBF  = OFF_QBF  + 33554432;        // 4 weights    8388608
constexpr size_t OFF_QKV  = OFF_WBF  + 8388608;         // Q,K,V bf16   100663296
constexpr size_t OFF_ATT  = OFF_QKV  + 100663296;       // attn bf16    33554432
constexpr size_t OFF_LAND = OFF_ATT  + 33554432;        // landmarks    262144
constexpr size_t OFF_LN   = OFF_LAND + 262144;          // |l|^2 f32    8192
constexpr size_t OFF_WK   = OFF_LN   + 8192;            // Winv f32     524288
constexpr size_t OFF_ZP   = OFF_WK   + 524288;          // Z partials   4194304
constexpr size_t OFF_SP   = OFF_ZP   + 4194304;         // sum partials 65536
constexpr size_t OFF_YT   = OFF_SP   + 65536;           // Y^T bf16     327680

DEV u16 f2bf(float f){
  u32 u = __builtin_bit_cast(u32, f);
  u32 r = (u + 0x7FFFu + ((u >> 16) & 1u)) >> 16;
  return (u16)r;
}
DEV float bf2f(u16 h){ u32 u = ((u32)h) << 16; return __builtin_bit_cast(float, u); }
DEV u16x8 ld8(const u16* p){ return *(const u16x8*)p; }
DEV f32x4 mfma16(u16x8 a, u16x8 b, f32x4 c){
  return __builtin_amdgcn_mfma_f32_16x16x32_bf16(
      __builtin_bit_cast(bf16x8, a), __builtin_bit_cast(bf16x8, b), c, 0, 0, 0);
}
// async global->LDS, 16B per lane; LDS dest is wave-uniform base + lane*16.
DEV void gld_lds16(void* lds, const void* g){
  __builtin_amdgcn_global_load_lds(
      (__attribute__((address_space(1))) void*)(uintptr_t)g,
      (__attribute__((address_space(3))) void*)(u32)(uintptr_t)lds,
      16, 0, 0);
}
DEV void vmwait4(){ asm volatile("s_waitcnt vmcnt(4)" ::: "memory"); }
DEV void vmwait0(){ asm volatile("s_waitcnt vmcnt(0)" ::: "memory"); }
DEV void barrier_pin(){
  __builtin_amdgcn_s_barrier();
  __builtin_amdgcn_sched_barrier(0);
}
// LDS physical<->logical byte permutation within a 16KB half-tile:
// rows are 128B (=32 banks), so fr contributes 0 bank spread; XOR the
// 16B-slot index (bits 4-6) with row bits 0-2 (bits 7-9). Involution.
DEV u32 swz(u32 a){ return a ^ (((a >> 7) & 7u) << 4); }
DEV float rdlane(float v, int l){
  return __builtin_bit_cast(float, __builtin_amdgcn_readlane(__builtin_bit_cast(int, v), l));
}

// ---------------- fp32 -> bf16 pack, all 5 tensors in one launch ----------------
// blocks [0,8192): query (2.097M groups); then 4 x 512 blocks per weight matrix.
__global__ __launch_bounds__(256) void k_cvt_all(
    const float* __restrict__ q,  const float* __restrict__ wq,
    const float* __restrict__ wk, const float* __restrict__ wv,
    const float* __restrict__ wo, u16* __restrict__ qbf, u16* __restrict__ wbf)
{
  const int b = blockIdx.x;
  const float* src; u16* dst; int g;
  if (b < 8192) {
    src = q; dst = qbf; g = b*256 + threadIdx.x;
  } else {
    const int w = (b - 8192) >> 9;
    src = (w == 0) ? wq : (w == 1) ? wk : (w == 2) ? wv : wo;
    dst = wbf + (size_t)w * EMB * EMB;
    g = ((b - 8192) & 511)*256 + threadIdx.x;
  }
  float t[8];
  *(float4*)&t[0] = ((const float4*)src)[2*g];
  *(float4*)&t[4] = ((const float4*)src)[2*g + 1];
  u16x8 o;
  #pragma unroll
  for (int j = 0; j < 8; ++j) o[j] = f2bf(t[j]);
  *(u16x8*)&dst[(size_t)g * 8] = o;
}

// ---------------- 256x256 GEMM, 6-phase (merged 3+4 / 7+8) ----------------
// C[m][n] = sum_k A[m][k] * W[n][k] (+bias). BK=64, 2 K-tiles/iter, 8 waves.
// MODE 0: fused QKV (3 weight mats, bf16 out). MODE 1: out-proj (f32 out).
template <int MODE>
__global__ __launch_bounds__(512, 2) void k_gemm256(
    const u16* __restrict__ A, const u16* __restrict__ Wb,
    const float* __restrict__ b0, const float* __restrict__ b1,
    const float* __restrict__ b2, u16* __restrict__ OutB, float* __restrict__ OutF)
{
  constexpr int NI = 8;                       // iterations (2 K-tiles each), K=1024
  __shared__ __align__(16) u16 lds[2][2][2][128*64];   // [buf][mat][half][row*64+k]
  const int tid = threadIdx.x, lane = tid & 63, wv = tid >> 6;
  const int wr = wv >> 2, wc = wv & 3;        // 2 x 4 wave grid
  const int fr = lane & 15, fk = (lane >> 4) * 8;

  constexpr int NBX = (MODE == 0) ? 12 : 4;
  constexpr int CPX = NBX * 64 / 8;           // blocks per XCD chunk
  const int lin = blockIdx.x + NBX * blockIdx.y;
  const int w = (lin & 7) * CPX + (lin >> 3); // bijective XCD chunk swizzle
  const int bxw = w % NBX, byw = w / NBX;
  const int wsel = (MODE == 0) ? (bxw >> 2) : 0;
  const int col0 = (MODE == 0) ? ((bxw & 3) * 256) : (bxw * 256);
  const int row0 = byw * 256;
  const u16* Bm = Wb + (size_t)wsel * EMB * EMB;

  // staging: linear LDS dest byte P holds logical byte swz(P)
  int voff[2]; u32 lo_[2];
  #pragma unroll
  for (int j = 0; j < 2; ++j) {
    u32 P  = (u32)((j*8 + wv) * 1024);
    u32 Pl = P + (u32)lane * 16;
    u32 L  = swz(Pl);
    voff[j] = (int)((L >> 7) * EMB + ((L >> 1) & 63));
    lo_[j]  = P;
  }
  // swizzled per-lane ds_read byte offsets (row = fr within each 16-row stripe)
  u32 qsw[2];
  #pragma unroll
  for (int ks = 0; ks < 2; ++ks)
    qsw[ks] = swz((u32)(fr*128 + ks*64 + fk*2));

  f32x4 acc[8][4] = {};
  u16x8 af[2][8], bfr[2][4];

  auto STAGE = [&](int buf, int mat, int half, int kt) {
    const u16* gb = (mat == 0)
      ? (A  + (size_t)(row0 + half*128) * EMB + kt*64)
      : (Bm + (size_t)(col0 + half*128) * EMB + kt*64);
    char* lb = (char*)&lds[buf][mat][half][0];
    #pragma unroll
    for (int j = 0; j < 2; ++j)
      gld_lds16(lb + lo_[j], gb + voff[j]);
  };
  auto LDA = [&](int buf, int m, int ks) -> u16x8 {
    return ld8((const u16*)((const char*)&lds[buf][0][wr][0] + m*2048 + qsw[ks]));
  };
  auto LDB = [&](int buf, int n, int ks) -> u16x8 {
    return ld8((const u16*)((const char*)&lds[buf][1][wc>>1][0]
                            + (wc&1)*8192 + n*2048 + qsw[ks]));
  };
  auto READ_LO = [&](int buf) {       // A m0-3 + B n0-1 (both ks): 12 ds_read_b128
    #pragma unroll
    for (int ks = 0; ks < 2; ++ks) {
      #pragma unroll
      for (int m = 0; m < 4; ++m) af[ks][m] = LDA(buf, m, ks);
      #pragma unroll
      for (int n = 0; n < 2; ++n) bfr[ks][n] = LDB(buf, n, ks);
    }
  };
  auto READ_HI = [&](int buf) {       // A m4-7 + B n2-3
    #pragma unroll
    for (int ks = 0; ks < 2; ++ks) {
      #pragma unroll
      for (int m = 0; m < 4; ++m) af[ks][4+m] = LDA(buf, 4+m, ks);
      #pragma unroll
      for (int n = 0; n < 2; ++n) bfr[ks][2+n] = LDB(buf, 2+n, ks);
    }
  };
  auto MFMAQ = [&](int mh, int nh) {  // one C-quadrant x K=64: 16 MFMA
    __builtin_amdgcn_s_setprio(1);
    #pragma unroll
    for (int ks = 0; ks < 2; ++ks)
      #pragma unroll
      for (int m = 0; m < 4; ++m)
        #pragma unroll
        for (int n = 0; n < 2; ++n) {
          const int mi = mh*4 + m, ni = nh*2 + n;
          acc[mi][ni] = mfma16(af[ks][mi], bfr[ks][ni], acc[mi][ni]);
        }
    __builtin_amdgcn_s_setprio(0);
  };

  // prologue: K0 full -> buf0; K1.A0,A1 -> buf1; wait K0 landed (4 left in flight)
  STAGE(0,0,0,0); STAGE(0,0,1,0); STAGE(0,1,0,0); STAGE(0,1,1,0);
  STAGE(1,0,0,1); STAGE(1,0,1,1);
  vmwait4();
  barrier_pin();

  #pragma unroll 1
  for (int it = 0; it < NI; ++it) {
    const int kt0 = 2*it;
    const bool last = (it == NI-1);
    // ph1: reads buf0 lo; stage (kt0+1).B0 -> buf1
    READ_LO(0); STAGE(1,1,0,kt0+1);
    barrier_pin(); MFMAQ(0,0); barrier_pin();
    // ph2: reads buf0 hi; stage (kt0+1).B1 -> buf1
    READ_HI(0); STAGE(1,1,1,kt0+1);
    barrier_pin(); MFMAQ(0,1); barrier_pin();
    // ph34: stage (kt0+2).A -> buf0; counted wait -> buf1 (kt0+1) fully landed
    if (!last) { STAGE(0,0,0,kt0+2); STAGE(0,0,1,kt0+2); vmwait4(); }
    else       { vmwait0(); }
    barrier_pin(); MFMAQ(1,1); MFMAQ(1,0); barrier_pin();
    // ph5: reads buf1 lo; stage (kt0+2).B0 -> buf0
    READ_LO(1); if (!last) STAGE(0,1,0,kt0+2);
    barrier_pin(); MFMAQ(0,0); barrier_pin();
    // ph6: reads buf1 hi; stage (kt0+2).B1 -> buf0
    READ_HI(1); if (!last) STAGE(0,1,1,kt0+2);
    barrier_pin(); MFMAQ(0,1); barrier_pin();
    // ph78: stage (kt0+3).A -> buf1; counted wait -> buf0 (kt0+2) fully landed
    if (!last) { STAGE(1,0,0,kt0+3); STAGE(1,0,1,kt0+3); vmwait4(); }
    barrier_pin(); MFMAQ(1,1); MFMAQ(1,0); barrier_pin();
  }

  // epilogue
  const int rgrp = (lane >> 4) * 4;
  if (MODE == 0) {
    const float* bias = (wsel == 0) ? b0 : ((wsel == 1) ? b1 : b2);
    u16* Out = OutB + (size_t)wsel * NTOK * EMB;
    #pragma unroll
    for (int m = 0; m < 8; ++m) {
      const int r0 = row0 + wr*128 + m*16 + rgrp;
      #pragma unroll
      for (int n = 0; n < 4; ++n) {
        const int c = col0 + wc*64 + n*16 + fr;
        const float bb = bias[c];
        #pragma unroll
        for (int j = 0; j < 4; ++j)
          Out[(size_t)(r0 + j)*EMB + c] = f2bf(acc[m][n][j] + bb);
      }
    }
  } else {
    #pragma unroll
    for (int m = 0; m < 8; ++m) {
      const int r0 = row0 + wr*128 + m*16 + rgrp;
      #pragma unroll
      for (int n = 0; n < 4; ++n) {
        const int c = col0 + wc*64 + n*16 + fr;
        const float bb = b0[c];
        #pragma unroll
        for (int j = 0; j < 4; ++j)
          OutF[(size_t)(r0 + j)*EMB + c] = acc[m][n][j] + bb;
      }
    }
  }
}

// ---------------- landmarks: gather, norms, W kernel + fused register GJ ----------------
// W built in padded LDS; wave 0 inverts it in registers (rotation GJ, identical
// arithmetic to R6's k_inv) and writes Winv to `winv`. One launch instead of two.
__global__ __launch_bounds__(256) void k_land(
    const u16* __restrict__ QKV, const int* __restrict__ lidx,
    const float* __restrict__ tempp,
    u16* __restrict__ land, float* __restrict__ lnorm, float* __restrict__ winv)
{
  const int bh = blockIdx.x;            // 0..31
  const int b = bh >> 4, h = bh & 15;
  const int tid = threadIdx.x;
  __shared__ __align__(16) u16 Ls[NLM*HD];
  __shared__ float Lns[NLM];
  __shared__ float Wm[64][65];
  const u16* Kp = QKV + (size_t)NTOK*EMB + (size_t)b*SEQL*EMB + h*HD;
  {
    const int l = tid >> 2, p = tid & 3;        // each thread: 16 u16
    const int row = lidx[l];
    const u16* src = Kp + (size_t)row*EMB + p*16;
    *(u32x4*)&Ls[l*64 + p*16]     = *(const u32x4*)src;
    *(u32x4*)&Ls[l*64 + p*16 + 8] = *(const u32x4*)(src + 8);
  }
  __syncthreads();
  if (tid < 64) {
    float s = 0;
    for (int d = 0; d < 64; ++d) { float v = bf2f(Ls[tid*64 + d]); s += v*v; }
    Lns[tid] = s;
  }
  __syncthreads();
  const float invt = 1.0f / tempp[0];
  for (int e = tid; e < 4096; e += 256) {
    const int i = e >> 6, j = e & 63;
    float dot = 0;
    for (int d = 0; d < 64; ++d) dot += bf2f(Ls[i*64 + d]) * bf2f(Ls[j*64 + d]);
    const float c = fmaxf(Lns[i] + Lns[j] - 2.0f*dot, 0.0f);
    Wm[i][j] = __expf(-c * invt) + (i == j ? 1e-6f : 0.0f);
  }
  for (int e = tid; e < 4096; e += 256) land[(size_t)bh*4096 + e] = Ls[e];
  if (tid < 64) lnorm[bh*64 + tid] = Lns[tid];
  __syncthreads();
  if (tid < 64) {                      // wave 0: register-resident rotation GJ
    const int lane = tid;
    float w[64];
    #pragma unroll
    for (int r = 0; r < 64; ++r) w[r] = Wm[r][lane];
    #pragma unroll 1
    for (int cp = 0; cp < 64; ++cp) {
      const float diag = rdlane(w[0], cp);
      const float inv  = 1.0f / diag;
      const float oneh = (lane == cp) ? 1.0f : 0.0f;
      const float pj = w[0] * inv + oneh * inv;
      const float newpiv = pj - oneh;
      #pragma unroll
      for (int r = 1; r < 64; ++r) {
        const float f = rdlane(w[r], cp);
        w[r-1] = w[r] - f * pj;
      }
      w[63] = newpiv;
    }
    float* wp = winv + (size_t)bh * 4096;
    #pragma unroll
    for (int r = 0; r < 64; ++r) wp[r*64 + lane] = w[r];
  }
}

// ---------------- reduce ZP/SP + apply Winv -> Y^T (bf16, 80x64) ----------------
__global__ __launch_bounds__(256) void k_apply(
    const float* __restrict__ winv, const float* __restrict__ ZP,
    const float* __restrict__ SP, u16* __restrict__ YT)
{
  const int bh = blockIdx.x;
  const int tid = threadIdx.x;
  __shared__ float Wi[64][65];
  __shared__ float Rh[64][66];
  for (int e = tid; e < 4096; e += 256) Wi[e >> 6][e & 63] = winv[(size_t)bh*4096 + e];
  for (int e = tid; e < 4096; e += 256) {
    float s = 0;
    #pragma unroll
    for (int c = 0; c < 8; ++c) s += ZP[((size_t)bh*8 + c)*4096 + e];
    Rh[e >> 6][e & 63] = s;
  }
  if (tid < 64) {
    float s = 0;
    #pragma unroll
    for (int c = 0; c < 8; ++c) s += SP[(bh*8 + c)*64 + tid];
    Rh[tid][64] = s;
  }
  __syncthreads();
  u16* yt = YT + (size_t)bh * 80 * 64;
  const int l = tid & 63, de0 = tid >> 6;
  for (int de = de0; de < 65; de += 4) {       // wave-uniform de -> Rh broadcast
    float s = 0;
    #pragma unroll
    for (int k = 0; k < 64; ++k) s += Wi[l][k] * Rh[k][de];
    yt[de*64 + l] = f2bf(s);
  }
  for (int e = tid; e < 15*64; e += 256) yt[65*64 + e] = 0;
}

// ---------------- Phi_K on the fly -> partial Z and column sums ----------------
__global__ __launch_bounds__(256) void k_phik(
    const u16* __restrict__ QKV, const u16* __restrict__ land,
    const float* __restrict__ lnorm, const float* __restrict__ tempp,
    float* __restrict__ ZP, float* __restrict__ SP)
{
  const int chunk = blockIdx.x;         // 0..7 (1024 rows each)
  const int bh = blockIdx.y;            // 0..31
  const int b = bh >> 4, h = bh & 15;
  const int tid = threadIdx.x, lane = tid & 63, wv = tid >> 6;
  const int fr = lane & 15, fk = (lane >> 4) * 8, rgrp = (lane >> 4) * 4;
  __shared__ __align__(16) u16 Ls[NLM*HD];
  __shared__ float Lns[NLM];
  __shared__ __align__(16) u16 phiT[4][NLM*32];   // per-wave [l][n32]
  __shared__ float zbuf[NLM*HD];
  __shared__ float wsum[4][NLM];

  for (int i = tid; i < 512; i += 256)
    *(u32x4*)&Ls[i*8] = *(const u32x4*)&land[(size_t)bh*4096 + (size_t)i*8];
  if (tid < 64) Lns[tid] = lnorm[bh*64 + tid];
  __syncthreads();

  const float invt = 1.0f / tempp[0];
  const u16* Kp = QKV + (size_t)NTOK*EMB   + (size_t)b*SEQL*EMB + h*HD;
  const u16* Vp = QKV + (size_t)2*NTOK*EMB + (size_t)b*SEQL*EMB + h*HD;

  u16x8 bl[2][4];
  #pragma unroll
  for (int ks = 0; ks < 2; ++ks)
    #pragma unroll
    for (int lt = 0; lt < 4; ++lt)
      bl[ks][lt] = ld8(&Ls[(lt*16 + fr)*64 + ks*32 + fk]);

  f32x4 zacc[4][4] = {};                 // [lt][dt]
  float pacc[4] = {0.f, 0.f, 0.f, 0.f};
  const int n0 = chunk*1024 + wv*256;

  for (int g = 0; g < 8; ++g) {          // 32 rows per group
    const int ng = n0 + g*32;
    u16x8 ak[2][2];
    #pragma unroll
    for (int rt = 0; rt < 2; ++rt)
      #pragma unroll
      for (int ks = 0; ks < 2; ++ks)
        ak[rt][ks] = ld8(Kp + (size_t)(ng + rt*16 + fr)*EMB + ks*32 + fk);
    float kn[2];
    #pragma unroll
    for (int rt = 0; rt < 2; ++rt) {
      float s = 0;
      #pragma unroll
      for (int ks = 0; ks < 2; ++ks)
        #pragma unroll
        for (int jj = 0; jj < 8; ++jj) { float v = bf2f(ak[rt][ks][jj]); s += v*v; }
      s += __shfl_xor(s, 16); s += __shfl_xor(s, 32);
      kn[rt] = s;
    }
    f32x4 ckl[2][4] = {};
    #pragma unroll
    for (int ks = 0; ks < 2; ++ks)
      #pragma unroll
      for (int rt = 0; rt < 2; ++rt)
        #pragma unroll
        for (int lt = 0; lt < 4; ++lt)
          ckl[rt][lt] = mfma16(ak[rt][ks], bl[ks][lt], ckl[rt][lt]);
    #pragma unroll
    for (int rt = 0; rt < 2; ++rt)
      #pragma unroll
      for (int lt = 0; lt < 4; ++lt)
        #pragma unroll
        for (int j = 0; j < 4; ++j) {
          const float knr = __shfl(kn[rt], rgrp + j);
          const float c = fmaxf(knr + Lns[lt*16 + fr] - 2.0f*ckl[rt][lt][j], 0.0f);
          const float ph = __expf(-c * invt);
          pacc[lt] += ph;
          phiT[wv][(lt*16 + fr)*32 + rt*16 + rgrp + j] = f2bf(ph);
        }
    u16x8 ap[4];
    #pragma unroll
    for (int lt = 0; lt < 4; ++lt) ap[lt] = ld8(&phiT[wv][(lt*16 + fr)*32 + fk]);
    #pragma unroll
    for (int dt = 0; dt < 4; ++dt) {
      u16x8 bvu;
      #pragma unroll
      for (int jj = 0; jj < 8; ++jj)
        bvu[jj] = Vp[(size_t)(ng + fk + jj)*EMB + dt*16 + fr];
      #pragma unroll
      for (int lt = 0; lt < 4; ++lt)
        zacc[lt][dt] = mfma16(ap[lt], bvu, zacc[lt][dt]);
    }
  }
  #pragma unroll
  for (int lt = 0; lt < 4; ++lt) {
    float s = pacc[lt];
    s += __shfl_xor(s, 16); s += __shfl_xor(s, 32);
    if (lane < 16) wsum[wv][lt*16 + lane] = s;
  }
  // deterministic cross-wave Z reduction
  for (int w = 0; w < 4; ++w) {
    __syncthreads();
    if (wv == w) {
      #pragma unroll
      for (int lt = 0; lt < 4; ++lt)
        #pragma unroll
        for (int dt = 0; dt < 4; ++dt)
          #pragma unroll
          for (int j = 0; j < 4; ++j) {
            const int l = lt*16 + rgrp + j, d = dt*16 + fr;
            if (w == 0) zbuf[l*64 + d]  = zacc[lt][dt][j];
            else        zbuf[l*64 + d] += zacc[lt][dt][j];
          }
    }
  }
  __syncthreads();
  float* zp = ZP + ((size_t)bh*8 + chunk)*4096;
  for (int e = tid; e < 4096; e += 256) zp[e] = zbuf[e];
  if (tid < 64)
    SP[(bh*8 + chunk)*64 + tid] = wsum[0][tid] + wsum[1][tid] + wsum[2][tid] + wsum[3][tid];
}

// ---------------- Phi_Q on the fly -> attn = (Phi_Q Y) / (Phi_Q y2) ----------------
__global__ __launch_bounds__(256) void k_out_attn(
    const u16* __restrict__ QKV, const u16* __restrict__ land,
    const float* __restrict__ lnorm, const float* __restrict__ tempp,
    const u16* __restrict__ YT, u16* __restrict__ attn)
{
  const int chunk = blockIdx.x;         // 0..63 (128 rows each)
  const int bh = blockIdx.y;
  const int b = bh >> 4, h = bh & 15;
  const int tid = threadIdx.x, lane = tid & 63, wv = tid >> 6;
  const int fr = lane & 15, fk = (lane >> 4) * 8, rgrp = (lane >> 4) * 4;
  __shared__ __align__(16) u16 Ls[NLM*HD];
  __shared__ float Lns[NLM];
  __shared__ __align__(16) u16 YTs[80*64];
  __shared__ __align__(16) u16 phin[4][32*64];

  for (int i = tid; i < 512; i += 256)
    *(u32x4*)&Ls[i*8] = *(const u32x4*)&land[(size_t)bh*4096 + (size_t)i*8];
  for (int i = tid; i < 640; i += 256)
    *(u32x4*)&YTs[i*8] = *(const u32x4*)&YT[(size_t)bh*5120 + (size_t)i*8];
  if (tid < 64) Lns[tid] = lnorm[bh*64 + tid];
  __syncthreads();

  const float invt = 1.0f / tempp[0];
  u16x8 bl[2][4], byf[2][5];
  #pragma unroll
  for (int ks = 0; ks < 2; ++ks) {
    #pragma unroll
    for (int lt = 0; lt < 4; ++lt) bl[ks][lt] = ld8(&Ls[(lt*16 + fr)*64 + ks*32 + fk]);
    #pragma unroll
    for (int dt = 0; dt < 5; ++dt) byf[ks][dt] = ld8(&YTs[(dt*16 + fr)*64 + ks*32 + fk]);
  }
  const u16* Qp = QKV + (size_t)b*SEQL*EMB + h*HD;
  const int n0 = chunk*128 + wv*32;
  u16x8 aq[2][2];
  #pragma unroll
  for (int rt = 0; rt < 2; ++rt)
    #pragma unroll
    for (int ks = 0; ks < 2; ++ks)
      aq[rt][ks] = ld8(Qp + (size_t)(n0 + rt*16 + fr)*EMB + ks*32 + fk);
  float qn[2];
  #pragma unroll
  for (int rt = 0; rt < 2; ++rt) {
    float s = 0;
    #pragma unroll
    for (int ks = 0; ks < 2; ++ks)
      #pragma unroll
      for (int jj = 0; jj < 8; ++jj) { float v = bf2f(aq[rt][ks][jj]); s += v*v; }
    s += __shfl_xor(s, 16); s += __shfl_xor(s, 32);
    qn[rt] = s;
  }
  f32x4 cql[2][4] = {};
  #pragma unroll
  for (int ks = 0; ks < 2; ++ks)
    #pragma unroll
    for (int rt = 0; rt < 2; ++rt)
      #pragma unroll
      for (int lt = 0; lt < 4; ++lt)
        cql[rt][lt] = mfma16(aq[rt][ks], bl[ks][lt], cql[rt][lt]);
  #pragma unroll
  for (int rt = 0; rt < 2; ++rt)
    #pragma unroll
    for (int lt = 0; lt < 4; ++lt)
      #pragma unroll
      for (int j = 0; j < 4; ++j) {
        const float knr = __shfl(qn[rt], rgrp + j);
        const float c = fmaxf(knr + Lns[lt*16 + fr] - 2.0f*cql[rt][lt][j], 0.0f);
        phin[wv][(rt*16 + rgrp + j)*64 + lt*16 + fr] = f2bf(__expf(-c * invt));
      }
  u16x8 ap[2][2];
  #pragma unroll
  for (int rt = 0; rt < 2; ++rt)
    #pragma unroll
    for (int ks = 0; ks < 2; ++ks)
      ap[rt][ks] = ld8(&phin[wv][(rt*16 + fr)*64 + ks*32 + fk]);
  f32x4 o[2][5] = {};
  #pragma unroll
  for (int ks = 0; ks < 2; ++ks)
    #pragma unroll
    for (int rt = 0; rt < 2; ++rt)
      #pragma unroll
      for (int dt = 0; dt < 5; ++dt)
        o[rt][dt] = mfma16(ap[rt][ks], byf[ks][dt], o[rt][dt]);
  u16* Apt = attn + (size_t)b*SEQL*EMB + h*HD;
  #pragma unroll
  for (int rt = 0; rt < 2; ++rt)
    #pragma unroll
    for (int j = 0; j < 4; ++j) {
      const float nv = fmaxf(__shfl(o[rt][4][j], lane & 48), 1e-10f);
      const float rn = 1.0f / nv;
      const int row = n0 + rt*16 + rgrp + j;
      #pragma unroll
      for (int dt = 0; dt < 4; ++dt)
        Apt[(size_t)row*EMB + dt*16 + fr] = f2bf(o[rt][dt][j] * rn);
    }
}

} // namespace

extern "C" void kernel_launch(void* const* d_in, const int* in_sizes, int n_in,
                              void* d_out, int out_size, void* d_ws, size_t ws_size,
                              hipStream_t stream) {
  (void)in_sizes; (void)n_in; (void)out_size; (void)ws_size;
  const float* query = (const float*)d_in[0];
  const float* Wq = (const float*)d_in[1];
  const float* bq = (const float*)d_in[2];
  const float* Wk = (const float*)d_in[3];
  const float* bk = (const float*)d_in[4];
  const float* Wv = (const float*)d_in[5];
  const float* bv = (const float*)d_in[6];
  const float* Wo = (const float*)d_in[7];
  const float* bo = (const float*)d_in[8];
  const float* temp = (const float*)d_in[9];
  const int*   lidx = (const int*)d_in[10];
  float* out = (float*)d_out;
  char* ws = (char*)d_ws;

  u16* qbf   = (u16*)(ws + OFF_QBF);
  u16* wbf   = (u16*)(ws + OFF_WBF);
  u16* qkv   = (u16*)(ws + OFF_QKV);
  u16* attn  = (u16*)(ws + OFF_ATT);
  u16* land  = (u16*)(ws + OFF_LAND);
  float* lnorm = (float*)(ws + OFF_LN);
  float* winv  = (float*)(ws + OFF_WK);
  float* ZP  = (float*)(ws + OFF_ZP);
  float* SP  = (float*)(ws + OFF_SP);
  u16* YT    = (u16*)(ws + OFF_YT);

  k_cvt_all<<<8192 + 4*512, 256, 0, stream>>>(query, Wq, Wk, Wv, Wo, qbf, wbf);

  k_gemm256<0><<<dim3(12, 64), 512, 0, stream>>>(qbf, wbf, bq, bk, bv, qkv, nullptr);
  k_land<<<32, 256, 0, stream>>>(qkv, lidx, temp, land, lnorm, winv);
  k_phik<<<dim3(8, 32), 256, 0, stream>>>(qkv, land, lnorm, temp, ZP, SP);
  k_apply<<<32, 256, 0, stream>>>(winv, ZP, SP, YT);
  k_out_attn<<<dim3(64, 32), 256, 0, stream>>>(qkv, land, lnorm, temp, YT, attn);
  k_gemm256<1><<<dim3(4, 64), 512, 0, stream>>>(attn, wbf + 3*EMB*EMB, bo, nullptr,
                                                nullptr, nullptr, out);
}

// Round 8
// 265.022 us; speedup vs baseline: 2.1611x; 1.0110x over previous
//
#include <hip/hip_runtime.h>
#include <stdint.h>

typedef unsigned short u16;
typedef unsigned int u32;
typedef __attribute__((ext_vector_type(8))) __bf16 bf16x8;
typedef __attribute__((ext_vector_type(8))) u16 u16x8;
typedef __attribute__((ext_vector_type(4))) float f32x4;
typedef __attribute__((ext_vector_type(4))) u32 u32x4;

#define DEV static __device__ __forceinline__

namespace {

constexpr int NB2  = 2;
constexpr int SEQL = 8192;
constexpr int EMB  = 1024;
constexpr int HD   = 64;
constexpr int NLM  = 64;
constexpr int NTOK = NB2 * SEQL;   // 16384

// workspace layout (bytes)
constexpr size_t OFF_QBF  = 0;                          // query bf16   33554432
constexpr size_t OFF_WBF  = OFF_QBF  + 33554432;        // 4 weights    8388608
constexpr size_t OFF_QKV  = OFF_WBF  + 8388608;         // Q,K,V bf16   100663296
constexpr size_t OFF_ATT  = OFF_QKV  + 100663296;       // attn bf16    33554432
constexpr size_t OFF_LAND = OFF_ATT  + 33554432;        // landmarks    262144
constexpr size_t OFF_LN   = OFF_LAND + 262144;          // |l|^2 f32    8192
constexpr size_t OFF_WK   = OFF_LN   + 8192;            // Winv f32     524288
constexpr size_t OFF_ZP   = OFF_WK   + 524288;          // Z partials   4194304
constexpr size_t OFF_SP   = OFF_ZP   + 4194304;         // sum partials 65536
constexpr size_t OFF_YT   = OFF_SP   + 65536;           // Y^T bf16     327680

DEV u16 f2bf(float f){
  u32 u = __builtin_bit_cast(u32, f);
  u32 r = (u + 0x7FFFu + ((u >> 16) & 1u)) >> 16;
  return (u16)r;
}
DEV float bf2f(u16 h){ u32 u = ((u32)h) << 16; return __builtin_bit_cast(float, u); }
DEV u16x8 ld8(const u16* p){ return *(const u16x8*)p; }
DEV f32x4 mfma16(u16x8 a, u16x8 b, f32x4 c){
  return __builtin_amdgcn_mfma_f32_16x16x32_bf16(
      __builtin_bit_cast(bf16x8, a), __builtin_bit_cast(bf16x8, b), c, 0, 0, 0);
}
// async global->LDS, 16B per lane; LDS dest is wave-uniform base + lane*16.
DEV void gld_lds16(void* lds, const void* g){
  __builtin_amdgcn_global_load_lds(
      (__attribute__((address_space(1))) void*)(uintptr_t)g,
      (__attribute__((address_space(3))) void*)(u32)(uintptr_t)lds,
      16, 0, 0);
}
DEV void vmwait4(){ asm volatile("s_waitcnt vmcnt(4)" ::: "memory"); }
DEV void vmwait0(){ asm volatile("s_waitcnt vmcnt(0)" ::: "memory"); }
DEV void barrier_pin(){
  __builtin_amdgcn_s_barrier();
  __builtin_amdgcn_sched_barrier(0);
}
// LDS physical<->logical byte permutation within a 16KB half-tile:
// rows are 128B (=32 banks), so fr contributes 0 bank spread; XOR the
// 16B-slot index (bits 4-6) with row bits 0-2 (bits 7-9). Involution.
DEV u32 swz(u32 a){ return a ^ (((a >> 7) & 7u) << 4); }
DEV float rdlane(float v, int l){
  return __builtin_bit_cast(float, __builtin_amdgcn_readlane(__builtin_bit_cast(int, v), l));
}

// ---------------- fp32 -> bf16 pack, all 5 tensors in one launch ----------------
// blocks [0,8192): query (2.097M groups); then 4 x 512 blocks per weight matrix.
__global__ __launch_bounds__(256) void k_cvt_all(
    const float* __restrict__ q,  const float* __restrict__ wq,
    const float* __restrict__ wk, const float* __restrict__ wv,
    const float* __restrict__ wo, u16* __restrict__ qbf, u16* __restrict__ wbf)
{
  const int b = blockIdx.x;
  const float* src; u16* dst; int g;
  if (b < 8192) {
    src = q; dst = qbf; g = b*256 + threadIdx.x;
  } else {
    const int w = (b - 8192) >> 9;
    src = (w == 0) ? wq : (w == 1) ? wk : (w == 2) ? wv : wo;
    dst = wbf + (size_t)w * EMB * EMB;
    g = ((b - 8192) & 511)*256 + threadIdx.x;
  }
  float t[8];
  *(float4*)&t[0] = ((const float4*)src)[2*g];
  *(float4*)&t[4] = ((const float4*)src)[2*g + 1];
  u16x8 o;
  #pragma unroll
  for (int j = 0; j < 8; ++j) o[j] = f2bf(t[j]);
  *(u16x8*)&dst[(size_t)g * 8] = o;
}

// ---------------- 256x256 GEMM, 6-phase (merged 3+4 / 7+8) ----------------
// C[m][n] = sum_k A[m][k] * W[n][k] (+bias). BK=64, 2 K-tiles/iter, 8 waves.
// MODE 0: fused QKV (3 weight mats, bf16 out). MODE 1: out-proj (f32 out).
// Block mapping: 8 row-panels pinned per XCD (A set = 4MB = L2), B-panel-major
// order within the XCD so concurrent blocks share 1-4 B-panels (L2-resident).
template <int MODE>
__global__ __launch_bounds__(512, 2) void k_gemm256(
    const u16* __restrict__ A, const u16* __restrict__ Wb,
    const float* __restrict__ b0, const float* __restrict__ b1,
    const float* __restrict__ b2, u16* __restrict__ OutB, float* __restrict__ OutF)
{
  constexpr int NI = 8;                       // iterations (2 K-tiles each), K=1024
  __shared__ __align__(16) u16 lds[2][2][2][128*64];   // [buf][mat][half][row*64+k]
  const int tid = threadIdx.x, lane = tid & 63, wv = tid >> 6;
  const int wr = wv >> 2, wc = wv & 3;        // 2 x 4 wave grid
  const int fr = lane & 15, fk = (lane >> 4) * 8;

  constexpr int NBX = (MODE == 0) ? 12 : 4;
  const int lin = blockIdx.x + NBX * blockIdx.y;
  const int xcd = lin & 7, i = lin >> 3;      // round-robin XCD assignment
  const int bxw = i >> 3;                     // B-panel-major within XCD
  const int byw = xcd * 8 + (i & 7);          // 8 row-panels pinned per XCD
  const int wsel = (MODE == 0) ? (bxw >> 2) : 0;
  const int col0 = (MODE == 0) ? ((bxw & 3) * 256) : (bxw * 256);
  const int row0 = byw * 256;
  const u16* Bm = Wb + (size_t)wsel * EMB * EMB;

  // staging: linear LDS dest byte P holds logical byte swz(P)
  int voff[2]; u32 lo_[2];
  #pragma unroll
  for (int j = 0; j < 2; ++j) {
    u32 P  = (u32)((j*8 + wv) * 1024);
    u32 Pl = P + (u32)lane * 16;
    u32 L  = swz(Pl);
    voff[j] = (int)((L >> 7) * EMB + ((L >> 1) & 63));
    lo_[j]  = P;
  }
  // swizzled per-lane ds_read byte offsets (row = fr within each 16-row stripe)
  u32 qsw[2];
  #pragma unroll
  for (int ks = 0; ks < 2; ++ks)
    qsw[ks] = swz((u32)(fr*128 + ks*64 + fk*2));

  f32x4 acc[8][4] = {};
  u16x8 af[2][8], bfr[2][4];

  auto STAGE = [&](int buf, int mat, int half, int kt) {
    const u16* gb = (mat == 0)
      ? (A  + (size_t)(row0 + half*128) * EMB + kt*64)
      : (Bm + (size_t)(col0 + half*128) * EMB + kt*64);
    char* lb = (char*)&lds[buf][mat][half][0];
    #pragma unroll
    for (int j = 0; j < 2; ++j)
      gld_lds16(lb + lo_[j], gb + voff[j]);
  };
  auto LDA = [&](int buf, int m, int ks) -> u16x8 {
    return ld8((const u16*)((const char*)&lds[buf][0][wr][0] + m*2048 + qsw[ks]));
  };
  auto LDB = [&](int buf, int n, int ks) -> u16x8 {
    return ld8((const u16*)((const char*)&lds[buf][1][wc>>1][0]
                            + (wc&1)*8192 + n*2048 + qsw[ks]));
  };
  auto READ_LO = [&](int buf) {       // A m0-3 + B n0-1 (both ks): 12 ds_read_b128
    #pragma unroll
    for (int ks = 0; ks < 2; ++ks) {
      #pragma unroll
      for (int m = 0; m < 4; ++m) af[ks][m] = LDA(buf, m, ks);
      #pragma unroll
      for (int n = 0; n < 2; ++n) bfr[ks][n] = LDB(buf, n, ks);
    }
  };
  auto READ_HI = [&](int buf) {       // A m4-7 + B n2-3
    #pragma unroll
    for (int ks = 0; ks < 2; ++ks) {
      #pragma unroll
      for (int m = 0; m < 4; ++m) af[ks][4+m] = LDA(buf, 4+m, ks);
      #pragma unroll
      for (int n = 0; n < 2; ++n) bfr[ks][2+n] = LDB(buf, 2+n, ks);
    }
  };
  auto MFMAQ = [&](int mh, int nh) {  // one C-quadrant x K=64: 16 MFMA
    __builtin_amdgcn_s_setprio(1);
    #pragma unroll
    for (int ks = 0; ks < 2; ++ks)
      #pragma unroll
      for (int m = 0; m < 4; ++m)
        #pragma unroll
        for (int n = 0; n < 2; ++n) {
          const int mi = mh*4 + m, ni = nh*2 + n;
          acc[mi][ni] = mfma16(af[ks][mi], bfr[ks][ni], acc[mi][ni]);
        }
    __builtin_amdgcn_s_setprio(0);
  };

  // prologue: K0 full -> buf0; K1.A0,A1 -> buf1; wait K0 landed (4 left in flight)
  STAGE(0,0,0,0); STAGE(0,0,1,0); STAGE(0,1,0,0); STAGE(0,1,1,0);
  STAGE(1,0,0,1); STAGE(1,0,1,1);
  vmwait4();
  barrier_pin();

  #pragma unroll 1
  for (int it = 0; it < NI; ++it) {
    const int kt0 = 2*it;
    const bool last = (it == NI-1);
    // ph1: reads buf0 lo; stage (kt0+1).B0 -> buf1
    READ_LO(0); STAGE(1,1,0,kt0+1);
    barrier_pin(); MFMAQ(0,0); barrier_pin();
    // ph2: reads buf0 hi; stage (kt0+1).B1 -> buf1
    READ_HI(0); STAGE(1,1,1,kt0+1);
    barrier_pin(); MFMAQ(0,1); barrier_pin();
    // ph34: stage (kt0+2).A -> buf0; counted wait -> buf1 (kt0+1) fully landed
    if (!last) { STAGE(0,0,0,kt0+2); STAGE(0,0,1,kt0+2); vmwait4(); }
    else       { vmwait0(); }
    barrier_pin(); MFMAQ(1,1); MFMAQ(1,0); barrier_pin();
    // ph5: reads buf1 lo; stage (kt0+2).B0 -> buf0
    READ_LO(1); if (!last) STAGE(0,1,0,kt0+2);
    barrier_pin(); MFMAQ(0,0); barrier_pin();
    // ph6: reads buf1 hi; stage (kt0+2).B1 -> buf0
    READ_HI(1); if (!last) STAGE(0,1,1,kt0+2);
    barrier_pin(); MFMAQ(0,1); barrier_pin();
    // ph78: stage (kt0+3).A -> buf1; counted wait -> buf0 (kt0+2) fully landed
    if (!last) { STAGE(1,0,0,kt0+3); STAGE(1,0,1,kt0+3); vmwait4(); }
    barrier_pin(); MFMAQ(1,1); MFMAQ(1,0); barrier_pin();
  }

  // epilogue
  const int rgrp = (lane >> 4) * 4;
  if (MODE == 0) {
    const float* bias = (wsel == 0) ? b0 : ((wsel == 1) ? b1 : b2);
    u16* Out = OutB + (size_t)wsel * NTOK * EMB;
    #pragma unroll
    for (int m = 0; m < 8; ++m) {
      const int r0 = row0 + wr*128 + m*16 + rgrp;
      #pragma unroll
      for (int n = 0; n < 4; ++n) {
        const int c = col0 + wc*64 + n*16 + fr;
        const float bb = bias[c];
        #pragma unroll
        for (int j = 0; j < 4; ++j)
          Out[(size_t)(r0 + j)*EMB + c] = f2bf(acc[m][n][j] + bb);
      }
    }
  } else {
    #pragma unroll
    for (int m = 0; m < 8; ++m) {
      const int r0 = row0 + wr*128 + m*16 + rgrp;
      #pragma unroll
      for (int n = 0; n < 4; ++n) {
        const int c = col0 + wc*64 + n*16 + fr;
        const float bb = b0[c];
        #pragma unroll
        for (int j = 0; j < 4; ++j)
          OutF[(size_t)(r0 + j)*EMB + c] = acc[m][n][j] + bb;
      }
    }
  }
}

// ---------------- landmarks: gather, norms, W kernel + fused register GJ ----------------
__global__ __launch_bounds__(256) void k_land(
    const u16* __restrict__ QKV, const int* __restrict__ lidx,
    const float* __restrict__ tempp,
    u16* __restrict__ land, float* __restrict__ lnorm, float* __restrict__ winv)
{
  const int bh = blockIdx.x;            // 0..31
  const int b = bh >> 4, h = bh & 15;
  const int tid = threadIdx.x;
  __shared__ __align__(16) u16 Ls[NLM*HD];
  __shared__ float Lns[NLM];
  __shared__ float Wm[64][65];
  const u16* Kp = QKV + (size_t)NTOK*EMB + (size_t)b*SEQL*EMB + h*HD;
  {
    const int l = tid >> 2, p = tid & 3;        // each thread: 16 u16
    const int row = lidx[l];
    const u16* src = Kp + (size_t)row*EMB + p*16;
    *(u32x4*)&Ls[l*64 + p*16]     = *(const u32x4*)src;
    *(u32x4*)&Ls[l*64 + p*16 + 8] = *(const u32x4*)(src + 8);
  }
  __syncthreads();
  if (tid < 64) {
    float s = 0;
    for (int d = 0; d < 64; ++d) { float v = bf2f(Ls[tid*64 + d]); s += v*v; }
    Lns[tid] = s;
  }
  __syncthreads();
  const float invt = 1.0f / tempp[0];
  for (int e = tid; e < 4096; e += 256) {
    const int i = e >> 6, j = e & 63;
    float dot = 0;
    for (int d = 0; d < 64; ++d) dot += bf2f(Ls[i*64 + d]) * bf2f(Ls[j*64 + d]);
    const float c = fmaxf(Lns[i] + Lns[j] - 2.0f*dot, 0.0f);
    Wm[i][j] = __expf(-c * invt) + (i == j ? 1e-6f : 0.0f);
  }
  for (int e = tid; e < 4096; e += 256) land[(size_t)bh*4096 + e] = Ls[e];
  if (tid < 64) lnorm[bh*64 + tid] = Lns[tid];
  __syncthreads();
  if (tid < 64) {                      // wave 0: register-resident rotation GJ
    const int lane = tid;
    float w[64];
    #pragma unroll
    for (int r = 0; r < 64; ++r) w[r] = Wm[r][lane];
    #pragma unroll 1
    for (int cp = 0; cp < 64; ++cp) {
      const float diag = rdlane(w[0], cp);
      const float inv  = 1.0f / diag;
      const float oneh = (lane == cp) ? 1.0f : 0.0f;
      const float pj = w[0] * inv + oneh * inv;
      const float newpiv = pj - oneh;
      #pragma unroll
      for (int r = 1; r < 64; ++r) {
        const float f = rdlane(w[r], cp);
        w[r-1] = w[r] - f * pj;
      }
      w[63] = newpiv;
    }
    float* wp = winv + (size_t)bh * 4096;
    #pragma unroll
    for (int r = 0; r < 64; ++r) wp[r*64 + lane] = w[r];
  }
}

// ---------------- reduce ZP/SP + apply Winv -> Y^T (bf16, 80x64) ----------------
__global__ __launch_bounds__(256) void k_apply(
    const float* __restrict__ winv, const float* __restrict__ ZP,
    const float* __restrict__ SP, u16* __restrict__ YT)
{
  const int bh = blockIdx.x;
  const int tid = threadIdx.x;
  __shared__ float Wi[64][65];
  __shared__ float Rh[64][66];
  for (int e = tid; e < 4096; e += 256) Wi[e >> 6][e & 63] = winv[(size_t)bh*4096 + e];
  for (int e = tid; e < 4096; e += 256) {
    float s = 0;
    #pragma unroll
    for (int c = 0; c < 8; ++c) s += ZP[((size_t)bh*8 + c)*4096 + e];
    Rh[e >> 6][e & 63] = s;
  }
  if (tid < 64) {
    float s = 0;
    #pragma unroll
    for (int c = 0; c < 8; ++c) s += SP[(bh*8 + c)*64 + tid];
    Rh[tid][64] = s;
  }
  __syncthreads();
  u16* yt = YT + (size_t)bh * 80 * 64;
  const int l = tid & 63, de0 = tid >> 6;
  for (int de = de0; de < 65; de += 4) {       // wave-uniform de -> Rh broadcast
    float s = 0;
    #pragma unroll
    for (int k = 0; k < 64; ++k) s += Wi[l][k] * Rh[k][de];
    yt[de*64 + l] = f2bf(s);
  }
  for (int e = tid; e < 15*64; e += 256) yt[65*64 + e] = 0;
}

// ---------------- Phi_K on the fly -> partial Z and column sums ----------------
__global__ __launch_bounds__(256) void k_phik(
    const u16* __restrict__ QKV, const u16* __restrict__ land,
    const float* __restrict__ lnorm, const float* __restrict__ tempp,
    float* __restrict__ ZP, float* __restrict__ SP)
{
  const int chunk = blockIdx.x;         // 0..7 (1024 rows each)
  const int bh = blockIdx.y;            // 0..31
  const int b = bh >> 4, h = bh & 15;
  const int tid = threadIdx.x, lane = tid & 63, wv = tid >> 6;
  const int fr = lane & 15, fk = (lane >> 4) * 8, rgrp = (lane >> 4) * 4;
  __shared__ __align__(16) u16 Ls[NLM*HD];
  __shared__ float Lns[NLM];
  __shared__ __align__(16) u16 phiT[4][NLM*32];   // per-wave [l][n32]
  __shared__ float zbuf[NLM*HD];
  __shared__ float wsum[4][NLM];

  for (int i = tid; i < 512; i += 256)
    *(u32x4*)&Ls[i*8] = *(const u32x4*)&land[(size_t)bh*4096 + (size_t)i*8];
  if (tid < 64) Lns[tid] = lnorm[bh*64 + tid];
  __syncthreads();

  const float invt = 1.0f / tempp[0];
  const u16* Kp = QKV + (size_t)NTOK*EMB   + (size_t)b*SEQL*EMB + h*HD;
  const u16* Vp = QKV + (size_t)2*NTOK*EMB + (size_t)b*SEQL*EMB + h*HD;

  u16x8 bl[2][4];
  #pragma unroll
  for (int ks = 0; ks < 2; ++ks)
    #pragma unroll
    for (int lt = 0; lt < 4; ++lt)
      bl[ks][lt] = ld8(&Ls[(lt*16 + fr)*64 + ks*32 + fk]);

  f32x4 zacc[4][4] = {};                 // [lt][dt]
  float pacc[4] = {0.f, 0.f, 0.f, 0.f};
  const int n0 = chunk*1024 + wv*256;

  for (int g = 0; g < 8; ++g) {          // 32 rows per group
    const int ng = n0 + g*32;
    u16x8 ak[2][2];
    #pragma unroll
    for (int rt = 0; rt < 2; ++rt)
      #pragma unroll
      for (int ks = 0; ks < 2; ++ks)
        ak[rt][ks] = ld8(Kp + (size_t)(ng + rt*16 + fr)*EMB + ks*32 + fk);
    float kn[2];
    #pragma unroll
    for (int rt = 0; rt < 2; ++rt) {
      float s = 0;
      #pragma unroll
      for (int ks = 0; ks < 2; ++ks)
        #pragma unroll
        for (int jj = 0; jj < 8; ++jj) { float v = bf2f(ak[rt][ks][jj]); s += v*v; }
      s += __shfl_xor(s, 16); s += __shfl_xor(s, 32);
      kn[rt] = s;
    }
    f32x4 ckl[2][4] = {};
    #pragma unroll
    for (int ks = 0; ks < 2; ++ks)
      #pragma unroll
      for (int rt = 0; rt < 2; ++rt)
        #pragma unroll
        for (int lt = 0; lt < 4; ++lt)
          ckl[rt][lt] = mfma16(ak[rt][ks], bl[ks][lt], ckl[rt][lt]);
    #pragma unroll
    for (int rt = 0; rt < 2; ++rt)
      #pragma unroll
      for (int lt = 0; lt < 4; ++lt)
        #pragma unroll
        for (int j = 0; j < 4; ++j) {
          const float knr = __shfl(kn[rt], rgrp + j);
          const float c = fmaxf(knr + Lns[lt*16 + fr] - 2.0f*ckl[rt][lt][j], 0.0f);
          const float ph = __expf(-c * invt);
          pacc[lt] += ph;
          phiT[wv][(lt*16 + fr)*32 + rt*16 + rgrp + j] = f2bf(ph);
        }
    u16x8 ap[4];
    #pragma unroll
    for (int lt = 0; lt < 4; ++lt) ap[lt] = ld8(&phiT[wv][(lt*16 + fr)*32 + fk]);
    #pragma unroll
    for (int dt = 0; dt < 4; ++dt) {
      u16x8 bvu;
      #pragma unroll
      for (int jj = 0; jj < 8; ++jj)
        bvu[jj] = Vp[(size_t)(ng + fk + jj)*EMB + dt*16 + fr];
      #pragma unroll
      for (int lt = 0; lt < 4; ++lt)
        zacc[lt][dt] = mfma16(ap[lt], bvu, zacc[lt][dt]);
    }
  }
  #pragma unroll
  for (int lt = 0; lt < 4; ++lt) {
    float s = pacc[lt];
    s += __shfl_xor(s, 16); s += __shfl_xor(s, 32);
    if (lane < 16) wsum[wv][lt*16 + lane] = s;
  }
  // deterministic cross-wave Z reduction
  for (int w = 0; w < 4; ++w) {
    __syncthreads();
    if (wv == w) {
      #pragma unroll
      for (int lt = 0; lt < 4; ++lt)
        #pragma unroll
        for (int dt = 0; dt < 4; ++dt)
          #pragma unroll
          for (int j = 0; j < 4; ++j) {
            const int l = lt*16 + rgrp + j, d = dt*16 + fr;
            if (w == 0) zbuf[l*64 + d]  = zacc[lt][dt][j];
            else        zbuf[l*64 + d] += zacc[lt][dt][j];
          }
    }
  }
  __syncthreads();
  float* zp = ZP + ((size_t)bh*8 + chunk)*4096;
  for (int e = tid; e < 4096; e += 256) zp[e] = zbuf[e];
  if (tid < 64)
    SP[(bh*8 + chunk)*64 + tid] = wsum[0][tid] + wsum[1][tid] + wsum[2][tid] + wsum[3][tid];
}

// ---------------- Phi_Q on the fly -> attn = (Phi_Q Y) / (Phi_Q y2) ----------------
__global__ __launch_bounds__(256) void k_out_attn(
    const u16* __restrict__ QKV, const u16* __restrict__ land,
    const float* __restrict__ lnorm, const float* __restrict__ tempp,
    const u16* __restrict__ YT, u16* __restrict__ attn)
{
  const int chunk = blockIdx.x;         // 0..63 (128 rows each)
  const int bh = blockIdx.y;
  const int b = bh >> 4, h = bh & 15;
  const int tid = threadIdx.x, lane = tid & 63, wv = tid >> 6;
  const int fr = lane & 15, fk = (lane >> 4) * 8, rgrp = (lane >> 4) * 4;
  __shared__ __align__(16) u16 Ls[NLM*HD];
  __shared__ float Lns[NLM];
  __shared__ __align__(16) u16 YTs[80*64];
  __shared__ __align__(16) u16 phin[4][32*64];

  for (int i = tid; i < 512; i += 256)
    *(u32x4*)&Ls[i*8] = *(const u32x4*)&land[(size_t)bh*4096 + (size_t)i*8];
  for (int i = tid; i < 640; i += 256)
    *(u32x4*)&YTs[i*8] = *(const u32x4*)&YT[(size_t)bh*5120 + (size_t)i*8];
  if (tid < 64) Lns[tid] = lnorm[bh*64 + tid];
  __syncthreads();

  const float invt = 1.0f / tempp[0];
  u16x8 bl[2][4], byf[2][5];
  #pragma unroll
  for (int ks = 0; ks < 2; ++ks) {
    #pragma unroll
    for (int lt = 0; lt < 4; ++lt) bl[ks][lt] = ld8(&Ls[(lt*16 + fr)*64 + ks*32 + fk]);
    #pragma unroll
    for (int dt = 0; dt < 5; ++dt) byf[ks][dt] = ld8(&YTs[(dt*16 + fr)*64 + ks*32 + fk]);
  }
  const u16* Qp = QKV + (size_t)b*SEQL*EMB + h*HD;
  const int n0 = chunk*128 + wv*32;
  u16x8 aq[2][2];
  #pragma unroll
  for (int rt = 0; rt < 2; ++rt)
    #pragma unroll
    for (int ks = 0; ks < 2; ++ks)
      aq[rt][ks] = ld8(Qp + (size_t)(n0 + rt*16 + fr)*EMB + ks*32 + fk);
  float qn[2];
  #pragma unroll
  for (int rt = 0; rt < 2; ++rt) {
    float s = 0;
    #pragma unroll
    for (int ks = 0; ks < 2; ++ks)
      #pragma unroll
      for (int jj = 0; jj < 8; ++jj) { float v = bf2f(aq[rt][ks][jj]); s += v*v; }
    s += __shfl_xor(s, 16); s += __shfl_xor(s, 32);
    qn[rt] = s;
  }
  f32x4 cql[2][4] = {};
  #pragma unroll
  for (int ks = 0; ks < 2; ++ks)
    #pragma unroll
    for (int rt = 0; rt < 2; ++rt)
      #pragma unroll
      for (int lt = 0; lt < 4; ++lt)
        cql[rt][lt] = mfma16(aq[rt][ks], bl[ks][lt], cql[rt][lt]);
  #pragma unroll
  for (int rt = 0; rt < 2; ++rt)
    #pragma unroll
    for (int lt = 0; lt < 4; ++lt)
      #pragma unroll
      for (int j = 0; j < 4; ++j) {
        const float knr = __shfl(qn[rt], rgrp + j);
        const float c = fmaxf(knr + Lns[lt*16 + fr] - 2.0f*cql[rt][lt][j], 0.0f);
        phin[wv][(rt*16 + rgrp + j)*64 + lt*16 + fr] = f2bf(__expf(-c * invt));
      }
  u16x8 ap[2][2];
  #pragma unroll
  for (int rt = 0; rt < 2; ++rt)
    #pragma unroll
    for (int ks = 0; ks < 2; ++ks)
      ap[rt][ks] = ld8(&phin[wv][(rt*16 + fr)*64 + ks*32 + fk]);
  f32x4 o[2][5] = {};
  #pragma unroll
  for (int ks = 0; ks < 2; ++ks)
    #pragma unroll
    for (int rt = 0; rt < 2; ++rt)
      #pragma unroll
      for (int dt = 0; dt < 5; ++dt)
        o[rt][dt] = mfma16(ap[rt][ks], byf[ks][dt], o[rt][dt]);
  u16* Apt = attn + (size_t)b*SEQL*EMB + h*HD;
  #pragma unroll
  for (int rt = 0; rt < 2; ++rt)
    #pragma unroll
    for (int j = 0; j < 4; ++j) {
      const float nv = fmaxf(__shfl(o[rt][4][j], lane & 48), 1e-10f);
      const float rn = 1.0f / nv;
      const int row = n0 + rt*16 + rgrp + j;
      #pragma unroll
      for (int dt = 0; dt < 4; ++dt)
        Apt[(size_t)row*EMB + dt*16 + fr] = f2bf(o[rt][dt][j] * rn);
    }
}

} // namespace

extern "C" void kernel_launch(void* const* d_in, const int* in_sizes, int n_in,
                              void* d_out, int out_size, void* d_ws, size_t ws_size,
                              hipStream_t stream) {
  (void)in_sizes; (void)n_in; (void)out_size; (void)ws_size;
  const float* query = (const float*)d_in[0];
  const float* Wq = (const float*)d_in[1];
  const float* bq = (const float*)d_in[2];
  const float* Wk = (const float*)d_in[3];
  const float* bk = (const float*)d_in[4];
  const float* Wv = (const float*)d_in[5];
  const float* bv = (const float*)d_in[6];
  const float* Wo = (const float*)d_in[7];
  const float* bo = (const float*)d_in[8];
  const float* temp = (const float*)d_in[9];
  const int*   lidx = (const int*)d_in[10];
  float* out = (float*)d_out;
  char* ws = (char*)d_ws;

  u16* qbf   = (u16*)(ws + OFF_QBF);
  u16* wbf   = (u16*)(ws + OFF_WBF);
  u16* qkv   = (u16*)(ws + OFF_QKV);
  u16* attn  = (u16*)(ws + OFF_ATT);
  u16* land  = (u16*)(ws + OFF_LAND);
  float* lnorm = (float*)(ws + OFF_LN);
  float* winv  = (float*)(ws + OFF_WK);
  float* ZP  = (float*)(ws + OFF_ZP);
  float* SP  = (float*)(ws + OFF_SP);
  u16* YT    = (u16*)(ws + OFF_YT);

  k_cvt_all<<<8192 + 4*512, 256, 0, stream>>>(query, Wq, Wk, Wv, Wo, qbf, wbf);

  k_gemm256<0><<<dim3(12, 64), 512, 0, stream>>>(qbf, wbf, bq, bk, bv, qkv, nullptr);
  k_land<<<32, 256, 0, stream>>>(qkv, lidx, temp, land, lnorm, winv);
  k_phik<<<dim3(8, 32), 256, 0, stream>>>(qkv, land, lnorm, temp, ZP, SP);
  k_apply<<<32, 256, 0, stream>>>(winv, ZP, SP, YT);
  k_out_attn<<<dim3(64, 32), 256, 0, stream>>>(qkv, land, lnorm, temp, YT, attn);
  k_gemm256<1><<<dim3(4, 64), 512, 0, stream>>>(attn, wbf + 3*EMB*EMB, bo, nullptr,
                                                nullptr, nullptr, out);
}